// Round 8
// baseline (272.362 us; speedup 1.0000x reference)
//
#include <hip/hip_runtime.h>
#include <hip/hip_fp16.h>
#include <math.h>

#define NN 16384
#define TM 32
#define LDA 132   // f32 LDS row stride (128 + 4 pad)
#define LDH 136   // f16 LDS row stride (128 + 8 pad, keeps 16B alignment)
#define LDDH 40   // dists f16 stride (80 B rows, 16B-aligned)
#define LDSH 24   // seqs f16 stride (48 B rows, 16B-aligned)

typedef unsigned int uint;
typedef unsigned short ushort;
typedef _Float16 half8 __attribute__((ext_vector_type(8)));
typedef _Float16 half2v __attribute__((ext_vector_type(2)));
typedef float floatx4 __attribute__((ext_vector_type(4)));

__device__ __forceinline__ uint pack2h(float a, float b) {
    _Float16 ha = (_Float16)a, hb = (_Float16)b;
    ushort ua = *(ushort*)&ha, ub = *(ushort*)&hb;
    return (uint)ua | ((uint)ub << 16);
}
__device__ __forceinline__ float2 h2f2(uint u) {
    __half2 h = *(__half2*)&u;
    return __half22float2(h);
}
// packed f16 pair dot with f32 accumulate — single v_dot2_f32_f16
__device__ __forceinline__ float dot_h2(uint a, uint b, float acc) {
    half2v ha = *(half2v*)&a, hb = *(half2v*)&b;
    return __builtin_amdgcn_fdot2(ha, hb, acc, false);
}
// f32 scalar × packed-f16 pair -> two f32 accumulators (2× v_fma_mix_f32)
__device__ __forceinline__ void fma2(float a, uint v, float& acc0, float& acc1) {
    __half2 h = *(__half2*)&v;
    acc0 += a * (float)__low2half(h);
    acc1 += a * (float)__high2half(h);
}

// ================= phaseA: MFMA f16 fused 6-GEMM chain + qext =================
// A-frag: A[m=lane&15][k=quad*8+j]  B-frag: B[k=quad*8+j][n=lane&15]
// C/D: col=lane&15, row=quad*4+reg (m89-verified).

struct Acc4 { floatx4 a[4]; };

template<bool RELUA>
__device__ __forceinline__ Acc4 mfma_gemm(const ushort* Ab, const half8* wp, int lane, int w)
{
    const int m  = (w & 1) * 16 + (lane & 15);
    const int kq = (lane >> 4) * 8;
    const int cg = w >> 1;
    half8 afr[4];
#pragma unroll
    for (int ks = 0; ks < 4; ++ks) {
        afr[ks] = *(const half8*)&Ab[m * LDH + ks * 32 + kq];
        if (RELUA) {
#pragma unroll
            for (int j = 0; j < 8; ++j)
                afr[ks][j] = afr[ks][j] > (_Float16)0.f ? afr[ks][j] : (_Float16)0.f;
        }
    }
    Acc4 r;
#pragma unroll
    for (int ct = 0; ct < 4; ++ct) {
        const int CT = cg * 4 + ct;
        floatx4 acc = {0.f, 0.f, 0.f, 0.f};
#pragma unroll
        for (int ks = 0; ks < 4; ++ks) {
            half8 bfr = wp[(CT * 4 + ks) * 64 + lane];
            acc = __builtin_amdgcn_mfma_f32_16x16x32_f16(afr[ks], bfr, acc, 0, 0, 0);
        }
        r.a[ct] = acc;
    }
    return r;
}

template<bool HAS_BIAS, bool RELU, bool HAS_ENC, bool F16OUT>
__device__ __forceinline__ void epilogue(const Acc4& ac, const float* __restrict__ bias,
    const float* __restrict__ enc, ushort* dst16, float* dst32,
    int node0, int lane, int w)
{
    const int row0 = (w & 1) * 16 + ((lane >> 4) << 2);
    const int cg = w >> 1;
#pragma unroll
    for (int ct = 0; ct < 4; ++ct) {
        const int col = (cg * 4 + ct) * 16 + (lane & 15);
        float bb = HAS_BIAS ? bias[col] : 0.f;
#pragma unroll
        for (int r = 0; r < 4; ++r) {
            float x = ac.a[ct][r] + bb;
            if (RELU) x = fmaxf(x, 0.f);
            if (HAS_ENC) x += enc[(size_t)(node0 + row0 + r) * 128 + col];
            if (F16OUT) {
                _Float16 h = (_Float16)x;
                dst16[(row0 + r) * LDH + col] = *(ushort*)&h;
            } else {
                dst32[(row0 + r) * LDA + col] = x;
            }
        }
    }
}

__global__ __launch_bounds__(256) void phaseA_kernel(
    const float* __restrict__ features, const float* __restrict__ enc,
    const float* __restrict__ b1, const float* __restrict__ b2,
    const float* __restrict__ b3, const float* __restrict__ bq,
    const float* __restrict__ Wk, const ushort* __restrict__ wpack,
    ushort* __restrict__ qext, ushort* __restrict__ kv)
{
    __shared__ __align__(16) ushort bufA[TM * LDH];
    __shared__ __align__(16) ushort bufB[TM * LDH];
    __shared__ __align__(16) float  qstage[TM * LDA];
    __shared__ __align__(16) float  wk[48 * 128];
    ushort* vstage = (ushort*)qstage;

    const int t = threadIdx.x;
    const int lane = t & 63, w = t >> 6;
    const int node0 = blockIdx.x * TM;

    const half8* wpQ = (const half8*)(wpack + 0 * 16384);
    const half8* wp1 = (const half8*)(wpack + 1 * 16384);
    const half8* wp2 = (const half8*)(wpack + 2 * 16384);
    const half8* wp3 = (const half8*)(wpack + 3 * 16384);
    const half8* wpK = (const half8*)(wpack + 4 * 16384);
    const half8* wpV = (const half8*)(wpack + 5 * 16384);

#pragma unroll
    for (int r = 0; r < 4; ++r) {
        int fid = t + 256 * r;
        int row = fid >> 5, c4 = (fid & 31) * 4;
        float4 v = *(const float4*)&features[(size_t)(node0 + row) * 128 + c4];
        uint2 h = make_uint2(pack2h(v.x, v.y), pack2h(v.z, v.w));
        *(uint2*)&bufA[row * LDH + c4] = h;
    }
#pragma unroll
    for (int r = 0; r < 6; ++r) {
        int fid = t + 256 * r;
        *(float4*)&wk[fid * 4] = *(const float4*)&Wk[128 * 128 + fid * 4];
    }
    __syncthreads();

    Acc4 aQ = mfma_gemm<false>(bufA, wpQ, lane, w);          // q = F@Wq
    Acc4 a1 = mfma_gemm<true >(bufA, wp1, lane, w);          // relu(F)@W1
    epilogue<true, false, false, false>(aQ, bq, nullptr, nullptr, qstage, node0, lane, w);
    epilogue<true, true,  false, true >(a1, b1, nullptr, bufB, nullptr, node0, lane, w);
    __syncthreads();

    Acc4 a2 = mfma_gemm<false>(bufB, wp2, lane, w);          // h1@W2

    // fused qext: per (node m, head hh): 48 ext dots + q copy, f16 out
    {
        const int m = t >> 3, hh = t & 7;
        float q[16];
#pragma unroll
        for (int jj = 0; jj < 4; ++jj)
            *(float4*)&q[jj * 4] = *(const float4*)&qstage[m * LDA + hh * 16 + jj * 4];
        ushort* dst = &qext[(size_t)(node0 + m) * 512 + hh * 64];
#pragma unroll
        for (int x0 = 0; x0 < 48; x0 += 8) {
            float res[8];
#pragma unroll
            for (int xx = 0; xx < 8; ++xx) {
                const float* wr = &wk[(x0 + xx) * 128 + hh * 16];
                float s = 0.f;
#pragma unroll
                for (int jj = 0; jj < 4; ++jj) {
                    float4 wv = *(const float4*)&wr[jj * 4];
                    s += q[jj*4+0]*wv.x + q[jj*4+1]*wv.y + q[jj*4+2]*wv.z + q[jj*4+3]*wv.w;
                }
                res[xx] = s;
            }
            *(uint4*)&dst[x0] = make_uint4(pack2h(res[0], res[1]), pack2h(res[2], res[3]),
                                           pack2h(res[4], res[5]), pack2h(res[6], res[7]));
        }
        *(uint4*)&dst[48] = make_uint4(pack2h(q[0], q[1]),  pack2h(q[2], q[3]),
                                       pack2h(q[4], q[5]),  pack2h(q[6], q[7]));
        *(uint4*)&dst[56] = make_uint4(pack2h(q[8], q[9]),  pack2h(q[10], q[11]),
                                       pack2h(q[12], q[13]), pack2h(q[14], q[15]));
    }
    epilogue<true, true, false, true>(a2, b2, nullptr, bufA, nullptr, node0, lane, w);
    __syncthreads();

    Acc4 a3 = mfma_gemm<false>(bufA, wp3, lane, w);          // h2@W3
    epilogue<true, true, true, true>(a3, b3, enc, bufB, nullptr, node0, lane, w);  // msg
    __syncthreads();

    Acc4 aK = mfma_gemm<false>(bufB, wpK, lane, w);          // msg@Wk[:128]
    Acc4 aV = mfma_gemm<false>(bufB, wpV, lane, w);          // msg@Wv[:128]
    epilogue<false, false, false, true>(aK, nullptr, nullptr, bufA,   nullptr, node0, lane, w);
    epilogue<false, false, false, true>(aV, nullptr, nullptr, vstage, nullptr, node0, lane, w);
    __syncthreads();

    {
        int row = t >> 3, c16 = (t & 7) * 16;
        size_t kbase = (size_t)(node0 + row) * 256;
        *(uint4*)&kv[kbase + c16]           = *(const uint4*)&bufA[row * LDH + c16];
        *(uint4*)&kv[kbase + c16 + 8]       = *(const uint4*)&bufA[row * LDH + c16 + 8];
        *(uint4*)&kv[kbase + 128 + c16]     = *(const uint4*)&vstage[row * LDH + c16];
        *(uint4*)&kv[kbase + 128 + c16 + 8] = *(const uint4*)&vstage[row * LDH + c16 + 8];
    }
}

// ===== merged prep: BigW/cvec (blocks 0..511) + wpack (blocks 512..703) =====
__global__ void prep_kernel(
    const float* __restrict__ Wv, const float* __restrict__ Wo,
    const float* __restrict__ bv, const float* __restrict__ bo,
    const float* __restrict__ W1, const float* __restrict__ W2,
    const float* __restrict__ W3, const float* __restrict__ Wq,
    const float* __restrict__ Wk,
    float* __restrict__ BigW, float* __restrict__ cvec,
    ushort* __restrict__ wpack)
{
    const int r = blockIdx.x;
    const int c = threadIdx.x;
    if (r < 512) {
        float s = 0.f;
        if (r < 128) {
            s = Wo[r * 128 + c];
        } else if (r < 384) {
            int x = r - 128; int hh = x >> 5, d = x & 31;
#pragma unroll
            for (int a = 0; a < 16; ++a)
                s += Wv[(128 + d) * 128 + hh * 16 + a] * Wo[(hh * 16 + a) * 128 + c];
        } else {
            int x = r - 384; int hh = x >> 4, ss = x & 15;
#pragma unroll
            for (int a = 0; a < 16; ++a)
                s += Wv[(160 + ss) * 128 + hh * 16 + a] * Wo[(hh * 16 + a) * 128 + c];
        }
        BigW[r * 128 + c] = s;
        if (r == 0) {
            float cv = bo[c];
            for (int jj = 0; jj < 128; ++jj) cv += bv[jj] * Wo[jj * 128 + c];
            cvec[c] = cv;
        }
    } else {
        if (c >= 64) return;
        const int bb = r - 512;          // 0..191
        const int g = bb >> 5;
        const int rem = bb & 31;
        const int CT = rem >> 2, ks = rem & 3;
        const float* W = (g == 0) ? Wq : (g == 1) ? W1 : (g == 2) ? W2
                       : (g == 3) ? W3 : (g == 4) ? Wk : Wv;
        const int n = CT * 16 + (c & 15);
        const int k0 = ks * 32 + (c >> 4) * 8;
        ushort out[8];
#pragma unroll
        for (int j = 0; j < 8; ++j) {
            _Float16 h = (_Float16)W[(k0 + j) * 128 + n];
            out[j] = *(ushort*)&h;
        }
        *(uint4*)&wpack[(size_t)(((g * 8 + CT) * 4 + ks) * 64 + c) * 8] = *(uint4*)out;
    }
}

// ==== attn: LDS-pipe relief — qext read from global (broadcast), no max-reduce ====
__global__ __launch_bounds__(256, 6) void attn_kernel(
    const ushort* __restrict__ qext, const ushort* __restrict__ kv,
    const float* __restrict__ dist, const float* __restrict__ seq,
    const int* __restrict__ idx, ushort* __restrict__ ovec)
{
    __shared__ __align__(16) ushort distsH[32 * LDDH];
    __shared__ __align__(16) ushort seqsH[32 * LDSH];
    __shared__ __align__(16) float attn_s[8 * 36];  // stride 36 -> conflict-free bcast
    __shared__ __align__(16) ushort kvv[32 * 128];

    const int t = threadIdx.x;
    const int n = blockIdx.x;
    const int h = t >> 5, k = t & 31;

    int j = idx[n * 32 + k];
    const uint4* mkp = (const uint4*)(kv + (size_t)j * 256 + h * 16);
    uint4 mk0 = mkp[0], mk1 = mkp[1];

    {   // msgv half -> LDS rows (8 threads/row)
        int r = t >> 3, cc = t & 7;
        int j2 = idx[n * 32 + r];
        const uint4* vp = (const uint4*)(kv + (size_t)j2 * 256 + 128 + cc * 16);
        uint4 v0 = vp[0], v1 = vp[1];
        *(uint4*)&kvv[r * 128 + cc * 16] = v0;
        *(uint4*)&kvv[r * 128 + cc * 16 + 8] = v1;
    }
    {   // dists -> f16, stride 40 halves
        float4 v = *(const float4*)&dist[(size_t)n * 1024 + t * 4];
        int kk = t >> 3, d0 = (t & 7) * 4;
        *(uint2*)&distsH[kk * LDDH + d0] = make_uint2(pack2h(v.x, v.y), pack2h(v.z, v.w));
    }
    if (t < 128) {   // seqs -> f16, stride 24 halves
        float4 v = *(const float4*)&seq[(size_t)n * 512 + t * 4];
        int kk = t >> 2, s0 = (t & 3) * 4;
        *(uint2*)&seqsH[kk * LDSH + s0] = make_uint2(pack2h(v.x, v.y), pack2h(v.z, v.w));
    }
    __syncthreads();

    {   // logits: 64 v_dot2_f32_f16; qext via broadcast GLOBAL reads (off the LDS pipe)
        const uint4* qg = (const uint4*)(qext + (size_t)n * 512 + h * 64);
        float lg = 0.f;
        uint4 q0 = qg[6], q1 = qg[7];   // q at halves 48..63
        lg = dot_h2(mk0.x, q0.x, lg); lg = dot_h2(mk0.y, q0.y, lg);
        lg = dot_h2(mk0.z, q0.z, lg); lg = dot_h2(mk0.w, q0.w, lg);
        lg = dot_h2(mk1.x, q1.x, lg); lg = dot_h2(mk1.y, q1.y, lg);
        lg = dot_h2(mk1.z, q1.z, lg); lg = dot_h2(mk1.w, q1.w, lg);
        const uint4* drp = (const uint4*)&distsH[k * LDDH];
#pragma unroll
        for (int i = 0; i < 4; ++i) {
            uint4 a = drp[i], b = qg[i];
            lg = dot_h2(a.x, b.x, lg); lg = dot_h2(a.y, b.y, lg);
            lg = dot_h2(a.z, b.z, lg); lg = dot_h2(a.w, b.w, lg);
        }
        const uint4* srp = (const uint4*)&seqsH[k * LDSH];
#pragma unroll
        for (int i = 0; i < 2; ++i) {
            uint4 a = srp[i], b = qg[4 + i];
            lg = dot_h2(a.x, b.x, lg); lg = dot_h2(a.y, b.y, lg);
            lg = dot_h2(a.z, b.z, lg); lg = dot_h2(a.w, b.w, lg);
        }
        lg *= 0.25f;   // 1/sqrt(ADIM=16)
        // logits are bounded (|lg| << 88): exp is f32-safe without max subtraction
        float e = __expf(lg);
        float sum = e;
#pragma unroll
        for (int off = 16; off; off >>= 1) sum += __shfl_xor(sum, off);
        attn_s[h * 36 + k] = e / sum;
    }
    __syncthreads();

    // single-pass epilogue: 2 output cols/thread, packed b32 LDS reads + v_fma_mix.
    // Branches align to wave boundaries.
    ushort* od = &ovec[(size_t)n * 512];
    if (t < 64) {               // o: cols 2t,2t+1 of msgv part
        const int hh = t >> 3;
        const float* ap = &attn_s[hh * 36];
        const ushort* src = &kvv[2 * t];
        float a0 = 0.f, a1 = 0.f;
#pragma unroll
        for (int i8 = 0; i8 < 8; ++i8) {
            float4 av = *(const float4*)&ap[i8 * 4];
            fma2(av.x, *(const uint*)&src[(i8 * 4 + 0) * 128], a0, a1);
            fma2(av.y, *(const uint*)&src[(i8 * 4 + 1) * 128], a0, a1);
            fma2(av.z, *(const uint*)&src[(i8 * 4 + 2) * 128], a0, a1);
            fma2(av.w, *(const uint*)&src[(i8 * 4 + 3) * 128], a0, a1);
        }
        *(uint*)&od[2 * t] = pack2h(a0, a1);
    } else if (t < 192) {       // wd: head hh, dist dims d0,d0+1
        const int i = t - 64;
        const int hh = i >> 4, d0 = (i & 15) * 2;
        const float* ap = &attn_s[hh * 36];
        const ushort* src = &distsH[d0];
        float a0 = 0.f, a1 = 0.f;
#pragma unroll
        for (int i8 = 0; i8 < 8; ++i8) {
            float4 av = *(const float4*)&ap[i8 * 4];
            fma2(av.x, *(const uint*)&src[(i8 * 4 + 0) * LDDH], a0, a1);
            fma2(av.y, *(const uint*)&src[(i8 * 4 + 1) * LDDH], a0, a1);
            fma2(av.z, *(const uint*)&src[(i8 * 4 + 2) * LDDH], a0, a1);
            fma2(av.w, *(const uint*)&src[(i8 * 4 + 3) * LDDH], a0, a1);
        }
        *(uint*)&od[128 + hh * 32 + d0] = pack2h(a0, a1);
    } else {                    // ws: head hh, seq dims s0,s0+1
        const int i = t - 192;
        const int hh = i >> 3, s0 = (i & 7) * 2;
        const float* ap = &attn_s[hh * 36];
        const ushort* src = &seqsH[s0];
        float a0 = 0.f, a1 = 0.f;
#pragma unroll
        for (int i8 = 0; i8 < 8; ++i8) {
            float4 av = *(const float4*)&ap[i8 * 4];
            fma2(av.x, *(const uint*)&src[(i8 * 4 + 0) * LDSH], a0, a1);
            fma2(av.y, *(const uint*)&src[(i8 * 4 + 1) * LDSH], a0, a1);
            fma2(av.z, *(const uint*)&src[(i8 * 4 + 2) * LDSH], a0, a1);
            fma2(av.w, *(const uint*)&src[(i8 * 4 + 3) * LDSH], a0, a1);
        }
        *(uint*)&od[384 + hh * 16 + s0] = pack2h(a0, a1);
    }
}

// ================= final: out = features + ovec(f16) @ BigW + cvec =================
__global__ __launch_bounds__(256) void final_kernel(
    const ushort* __restrict__ ovec, const float* __restrict__ BigW,
    const float* __restrict__ cvec, const float* __restrict__ features,
    float* __restrict__ out)
{
    __shared__ __align__(16) float bufA[TM * LDA];
    const int t = threadIdx.x;
    const int node0 = blockIdx.x * TM;
    const int m0 = (t >> 5) * 4;
    const int c0 = (t & 31) * 4;
    float acc[4][4];
#pragma unroll
    for (int mm = 0; mm < 4; ++mm)
#pragma unroll
        for (int cc = 0; cc < 4; ++cc) acc[mm][cc] = 0.f;

    for (int ck = 0; ck < 4; ++ck) {
        __syncthreads();
#pragma unroll
        for (int r = 0; r < 4; ++r) {
            int fid = t + 256 * r;
            int row = fid >> 5, c4 = (fid & 31) * 4;
            uint2 u = *(const uint2*)&ovec[(size_t)(node0 + row) * 512 + ck * 128 + c4];
            float2 a = h2f2(u.x), b = h2f2(u.y);
            *(float4*)&bufA[row * LDA + c4] = make_float4(a.x, a.y, b.x, b.y);
        }
        __syncthreads();
        const float* Wc = BigW + ck * 128 * 128;
#pragma unroll 4
        for (int ic = 0; ic < 32; ++ic) {
            float a[4][4];
#pragma unroll
            for (int mm = 0; mm < 4; ++mm) {
                float4 av = *(const float4*)&bufA[(m0 + mm) * LDA + ic * 4];
                a[mm][0] = av.x; a[mm][1] = av.y; a[mm][2] = av.z; a[mm][3] = av.w;
            }
            float w[4][4];
#pragma unroll
            for (int ii = 0; ii < 4; ++ii) {
                float4 wv = *(const float4*)&Wc[(ic * 4 + ii) * 128 + c0];
                w[ii][0] = wv.x; w[ii][1] = wv.y; w[ii][2] = wv.z; w[ii][3] = wv.w;
            }
#pragma unroll
            for (int mm = 0; mm < 4; ++mm)
#pragma unroll
                for (int ii = 0; ii < 4; ++ii) {
                    float av = a[mm][ii];
#pragma unroll
                    for (int cc = 0; cc < 4; ++cc)
                        acc[mm][cc] = fmaf(av, w[ii][cc], acc[mm][cc]);
                }
        }
    }
    float4 cv = *(const float4*)&cvec[c0];
#pragma unroll
    for (int mm = 0; mm < 4; ++mm) {
        float4 f = *(const float4*)&features[(size_t)(node0 + m0 + mm) * 128 + c0];
        *(float4*)&out[(size_t)(node0 + m0 + mm) * 128 + c0] =
            make_float4(acc[mm][0] + f.x + cv.x, acc[mm][1] + f.y + cv.y,
                        acc[mm][2] + f.z + cv.z, acc[mm][3] + f.w + cv.w);
    }
}

extern "C" void kernel_launch(void* const* d_in, const int* in_sizes, int n_in,
                              void* d_out, int out_size, void* d_ws, size_t ws_size,
                              hipStream_t stream)
{
    const float* features = (const float*)d_in[0];
    const float* dist     = (const float*)d_in[1];
    const float* seq      = (const float*)d_in[2];
    const float* enc      = (const float*)d_in[3];
    const int*   idx      = (const int*)d_in[4];
    const float* W1 = (const float*)d_in[5];
    const float* b1 = (const float*)d_in[6];
    const float* W2 = (const float*)d_in[7];
    const float* b2 = (const float*)d_in[8];
    const float* W3 = (const float*)d_in[9];
    const float* b3 = (const float*)d_in[10];
    const float* Wq = (const float*)d_in[11];
    const float* bq = (const float*)d_in[12];
    const float* Wk = (const float*)d_in[13];
    // d_in[14] = bk: dropped (softmax-invariant)
    const float* Wv = (const float*)d_in[15];
    const float* bv = (const float*)d_in[16];
    const float* Wo = (const float*)d_in[17];
    const float* bo = (const float*)d_in[18];
    float* out = (float*)d_out;

    // Workspace: kv 8 | qext 16 | ovec 16 | BigW 256K | cvec | wpack 192K  (~40.5 MB)
    char* ws = (char*)d_ws;
    ushort* kv    = (ushort*)ws;
    ushort* qext  = (ushort*)(ws + ((size_t)8  << 20));
    ushort* ovec  = (ushort*)(ws + ((size_t)24 << 20));
    float*  BigW  = (float*)(ws + ((size_t)40 << 20));
    float*  cvec  = (float*)(ws + ((size_t)40 << 20) + 262144);
    ushort* wpack = (ushort*)(ws + ((size_t)40 << 20) + 262144 + 512);

    prep_kernel<<<704, 128, 0, stream>>>(Wv, Wo, bv, bo, W1, W2, W3, Wq, Wk,
                                         BigW, cvec, wpack);
    phaseA_kernel<<<NN / TM, 256, 0, stream>>>(
        features, enc, b1, b2, b3, bq, Wk, wpack, qext, kv);
    attn_kernel<<<NN, 256, 0, stream>>>(qext, kv, dist, seq, idx, ovec);
    final_kernel<<<NN / TM, 256, 0, stream>>>(ovec, BigW, cvec, features, out);
}

// Round 9
// 270.430 us; speedup vs baseline: 1.0071x; 1.0071x over previous
//
#include <hip/hip_runtime.h>
#include <hip/hip_fp16.h>
#include <math.h>

#define NN 16384
#define TM 32
#define LDA 132   // f32 LDS row stride (128 + 4 pad)
#define LDH 136   // f16 LDS row stride (128 + 8 pad, keeps 16B alignment)
#define LDDH 40   // dists f16 stride (80 B rows, 16B-aligned)
#define LDSH 24   // seqs f16 stride (48 B rows, 16B-aligned)

typedef unsigned int uint;
typedef unsigned short ushort;
typedef _Float16 half8 __attribute__((ext_vector_type(8)));
typedef _Float16 half2v __attribute__((ext_vector_type(2)));
typedef float floatx4 __attribute__((ext_vector_type(4)));

__device__ __forceinline__ uint pack2h(float a, float b) {
    _Float16 ha = (_Float16)a, hb = (_Float16)b;
    ushort ua = *(ushort*)&ha, ub = *(ushort*)&hb;
    return (uint)ua | ((uint)ub << 16);
}
__device__ __forceinline__ float2 h2f2(uint u) {
    __half2 h = *(__half2*)&u;
    return __half22float2(h);
}
// packed f16 pair dot with f32 accumulate — single v_dot2_f32_f16
__device__ __forceinline__ float dot_h2(uint a, uint b, float acc) {
    half2v ha = *(half2v*)&a, hb = *(half2v*)&b;
    return __builtin_amdgcn_fdot2(ha, hb, acc, false);
}
// f32 scalar × packed-f16 pair -> two f32 accumulators (2× v_fma_mix_f32)
__device__ __forceinline__ void fma2(float a, uint v, float& acc0, float& acc1) {
    __half2 h = *(__half2*)&v;
    acc0 += a * (float)__low2half(h);
    acc1 += a * (float)__high2half(h);
}

// ================= phaseA: MFMA f16 fused 6-GEMM chain + qext =================
// A-frag: A[m=lane&15][k=quad*8+j]  B-frag: B[k=quad*8+j][n=lane&15]
// C/D: col=lane&15, row=quad*4+reg (m89-verified).

struct Acc4 { floatx4 a[4]; };

template<bool RELUA>
__device__ __forceinline__ Acc4 mfma_gemm(const ushort* Ab, const half8* wp, int lane, int w)
{
    const int m  = (w & 1) * 16 + (lane & 15);
    const int kq = (lane >> 4) * 8;
    const int cg = w >> 1;
    half8 afr[4];
#pragma unroll
    for (int ks = 0; ks < 4; ++ks) {
        afr[ks] = *(const half8*)&Ab[m * LDH + ks * 32 + kq];
        if (RELUA) {
#pragma unroll
            for (int j = 0; j < 8; ++j)
                afr[ks][j] = afr[ks][j] > (_Float16)0.f ? afr[ks][j] : (_Float16)0.f;
        }
    }
    Acc4 r;
#pragma unroll
    for (int ct = 0; ct < 4; ++ct) {
        const int CT = cg * 4 + ct;
        floatx4 acc = {0.f, 0.f, 0.f, 0.f};
#pragma unroll
        for (int ks = 0; ks < 4; ++ks) {
            half8 bfr = wp[(CT * 4 + ks) * 64 + lane];
            acc = __builtin_amdgcn_mfma_f32_16x16x32_f16(afr[ks], bfr, acc, 0, 0, 0);
        }
        r.a[ct] = acc;
    }
    return r;
}

template<bool HAS_BIAS, bool RELU, bool HAS_ENC, bool F16OUT>
__device__ __forceinline__ void epilogue(const Acc4& ac, const float* __restrict__ bias,
    const float* __restrict__ enc, ushort* dst16, float* dst32,
    int node0, int lane, int w)
{
    const int row0 = (w & 1) * 16 + ((lane >> 4) << 2);
    const int cg = w >> 1;
#pragma unroll
    for (int ct = 0; ct < 4; ++ct) {
        const int col = (cg * 4 + ct) * 16 + (lane & 15);
        float bb = HAS_BIAS ? bias[col] : 0.f;
#pragma unroll
        for (int r = 0; r < 4; ++r) {
            float x = ac.a[ct][r] + bb;
            if (RELU) x = fmaxf(x, 0.f);
            if (HAS_ENC) x += enc[(size_t)(node0 + row0 + r) * 128 + col];
            if (F16OUT) {
                _Float16 h = (_Float16)x;
                dst16[(row0 + r) * LDH + col] = *(ushort*)&h;
            } else {
                dst32[(row0 + r) * LDA + col] = x;
            }
        }
    }
}

__global__ __launch_bounds__(256) void phaseA_kernel(
    const float* __restrict__ features, const float* __restrict__ enc,
    const float* __restrict__ b1, const float* __restrict__ b2,
    const float* __restrict__ b3, const float* __restrict__ bq,
    const float* __restrict__ Wk, const ushort* __restrict__ wpack,
    ushort* __restrict__ qext, ushort* __restrict__ kv)
{
    __shared__ __align__(16) ushort bufA[TM * LDH];
    __shared__ __align__(16) ushort bufB[TM * LDH];
    __shared__ __align__(16) float  qstage[TM * LDA];
    __shared__ __align__(16) float  wk[48 * 128];
    ushort* vstage = (ushort*)qstage;

    const int t = threadIdx.x;
    const int lane = t & 63, w = t >> 6;
    const int node0 = blockIdx.x * TM;

    const half8* wpQ = (const half8*)(wpack + 0 * 16384);
    const half8* wp1 = (const half8*)(wpack + 1 * 16384);
    const half8* wp2 = (const half8*)(wpack + 2 * 16384);
    const half8* wp3 = (const half8*)(wpack + 3 * 16384);
    const half8* wpK = (const half8*)(wpack + 4 * 16384);
    const half8* wpV = (const half8*)(wpack + 5 * 16384);

#pragma unroll
    for (int r = 0; r < 4; ++r) {
        int fid = t + 256 * r;
        int row = fid >> 5, c4 = (fid & 31) * 4;
        float4 v = *(const float4*)&features[(size_t)(node0 + row) * 128 + c4];
        uint2 h = make_uint2(pack2h(v.x, v.y), pack2h(v.z, v.w));
        *(uint2*)&bufA[row * LDH + c4] = h;
    }
#pragma unroll
    for (int r = 0; r < 6; ++r) {
        int fid = t + 256 * r;
        *(float4*)&wk[fid * 4] = *(const float4*)&Wk[128 * 128 + fid * 4];
    }
    __syncthreads();

    Acc4 aQ = mfma_gemm<false>(bufA, wpQ, lane, w);          // q = F@Wq
    Acc4 a1 = mfma_gemm<true >(bufA, wp1, lane, w);          // relu(F)@W1
    epilogue<true, false, false, false>(aQ, bq, nullptr, nullptr, qstage, node0, lane, w);
    epilogue<true, true,  false, true >(a1, b1, nullptr, bufB, nullptr, node0, lane, w);
    __syncthreads();

    Acc4 a2 = mfma_gemm<false>(bufB, wp2, lane, w);          // h1@W2

    // fused qext: per (node m, head hh): 48 ext dots + q copy, f16 out
    {
        const int m = t >> 3, hh = t & 7;
        float q[16];
#pragma unroll
        for (int jj = 0; jj < 4; ++jj)
            *(float4*)&q[jj * 4] = *(const float4*)&qstage[m * LDA + hh * 16 + jj * 4];
        ushort* dst = &qext[(size_t)(node0 + m) * 512 + hh * 64];
#pragma unroll
        for (int x0 = 0; x0 < 48; x0 += 8) {
            float res[8];
#pragma unroll
            for (int xx = 0; xx < 8; ++xx) {
                const float* wr = &wk[(x0 + xx) * 128 + hh * 16];
                float s = 0.f;
#pragma unroll
                for (int jj = 0; jj < 4; ++jj) {
                    float4 wv = *(const float4*)&wr[jj * 4];
                    s += q[jj*4+0]*wv.x + q[jj*4+1]*wv.y + q[jj*4+2]*wv.z + q[jj*4+3]*wv.w;
                }
                res[xx] = s;
            }
            *(uint4*)&dst[x0] = make_uint4(pack2h(res[0], res[1]), pack2h(res[2], res[3]),
                                           pack2h(res[4], res[5]), pack2h(res[6], res[7]));
        }
        *(uint4*)&dst[48] = make_uint4(pack2h(q[0], q[1]),  pack2h(q[2], q[3]),
                                       pack2h(q[4], q[5]),  pack2h(q[6], q[7]));
        *(uint4*)&dst[56] = make_uint4(pack2h(q[8], q[9]),  pack2h(q[10], q[11]),
                                       pack2h(q[12], q[13]), pack2h(q[14], q[15]));
    }
    epilogue<true, true, false, true>(a2, b2, nullptr, bufA, nullptr, node0, lane, w);
    __syncthreads();

    Acc4 a3 = mfma_gemm<false>(bufA, wp3, lane, w);          // h2@W3
    epilogue<true, true, true, true>(a3, b3, enc, bufB, nullptr, node0, lane, w);  // msg
    __syncthreads();

    Acc4 aK = mfma_gemm<false>(bufB, wpK, lane, w);          // msg@Wk[:128]
    Acc4 aV = mfma_gemm<false>(bufB, wpV, lane, w);          // msg@Wv[:128]
    epilogue<false, false, false, true>(aK, nullptr, nullptr, bufA,   nullptr, node0, lane, w);
    epilogue<false, false, false, true>(aV, nullptr, nullptr, vstage, nullptr, node0, lane, w);
    __syncthreads();

    {
        int row = t >> 3, c16 = (t & 7) * 16;
        size_t kbase = (size_t)(node0 + row) * 256;
        *(uint4*)&kv[kbase + c16]           = *(const uint4*)&bufA[row * LDH + c16];
        *(uint4*)&kv[kbase + c16 + 8]       = *(const uint4*)&bufA[row * LDH + c16 + 8];
        *(uint4*)&kv[kbase + 128 + c16]     = *(const uint4*)&vstage[row * LDH + c16];
        *(uint4*)&kv[kbase + 128 + c16 + 8] = *(const uint4*)&vstage[row * LDH + c16 + 8];
    }
}

// ===== merged prep: BigW/cvec (blocks 0..511) + wpack (blocks 512..703) =====
__global__ void prep_kernel(
    const float* __restrict__ Wv, const float* __restrict__ Wo,
    const float* __restrict__ bv, const float* __restrict__ bo,
    const float* __restrict__ W1, const float* __restrict__ W2,
    const float* __restrict__ W3, const float* __restrict__ Wq,
    const float* __restrict__ Wk,
    float* __restrict__ BigW, float* __restrict__ cvec,
    ushort* __restrict__ wpack)
{
    const int r = blockIdx.x;
    const int c = threadIdx.x;
    if (r < 512) {
        float s = 0.f;
        if (r < 128) {
            s = Wo[r * 128 + c];
        } else if (r < 384) {
            int x = r - 128; int hh = x >> 5, d = x & 31;
#pragma unroll
            for (int a = 0; a < 16; ++a)
                s += Wv[(128 + d) * 128 + hh * 16 + a] * Wo[(hh * 16 + a) * 128 + c];
        } else {
            int x = r - 384; int hh = x >> 4, ss = x & 15;
#pragma unroll
            for (int a = 0; a < 16; ++a)
                s += Wv[(160 + ss) * 128 + hh * 16 + a] * Wo[(hh * 16 + a) * 128 + c];
        }
        BigW[r * 128 + c] = s;
        if (r == 0) {
            float cv = bo[c];
            for (int jj = 0; jj < 128; ++jj) cv += bv[jj] * Wo[jj * 128 + c];
            cvec[c] = cv;
        }
    } else {
        if (c >= 64) return;
        const int bb = r - 512;          // 0..191
        const int g = bb >> 5;
        const int rem = bb & 31;
        const int CT = rem >> 2, ks = rem & 3;
        const float* W = (g == 0) ? Wq : (g == 1) ? W1 : (g == 2) ? W2
                       : (g == 3) ? W3 : (g == 4) ? Wk : Wv;
        const int n = CT * 16 + (c & 15);
        const int k0 = ks * 32 + (c >> 4) * 8;
        ushort out[8];
#pragma unroll
        for (int j = 0; j < 8; ++j) {
            _Float16 h = (_Float16)W[(k0 + j) * 128 + n];
            out[j] = *(ushort*)&h;
        }
        *(uint4*)&wpack[(size_t)(((g * 8 + CT) * 4 + ks) * 64 + c) * 8] = *(uint4*)out;
    }
}

// ==== attn: qext global broadcast PREFETCHED before staging (latency hidden) ====
__global__ __launch_bounds__(256, 6) void attn_kernel(
    const ushort* __restrict__ qext, const ushort* __restrict__ kv,
    const float* __restrict__ dist, const float* __restrict__ seq,
    const int* __restrict__ idx, ushort* __restrict__ ovec)
{
    __shared__ __align__(16) ushort distsH[32 * LDDH];
    __shared__ __align__(16) ushort seqsH[32 * LDSH];
    __shared__ __align__(16) float attn_s[8 * 36];  // stride 36 -> conflict-free bcast
    __shared__ __align__(16) ushort kvv[32 * 128];

    const int t = threadIdx.x;
    const int n = blockIdx.x;
    const int h = t >> 5, k = t & 31;

    // ---- issue qext loads FIRST: latency hides under the whole staging phase ----
    const uint4* qg = (const uint4*)(qext + (size_t)n * 512 + h * 64);
    uint4 qv0 = qg[0], qv1 = qg[1], qv2 = qg[2], qv3 = qg[3];
    uint4 qv4 = qg[4], qv5 = qg[5], qv6 = qg[6], qv7 = qg[7];

    int j = idx[n * 32 + k];
    const uint4* mkp = (const uint4*)(kv + (size_t)j * 256 + h * 16);
    uint4 mk0 = mkp[0], mk1 = mkp[1];

    {   // msgv half -> LDS rows (8 threads/row)
        int r = t >> 3, cc = t & 7;
        int j2 = idx[n * 32 + r];
        const uint4* vp = (const uint4*)(kv + (size_t)j2 * 256 + 128 + cc * 16);
        uint4 v0 = vp[0], v1 = vp[1];
        *(uint4*)&kvv[r * 128 + cc * 16] = v0;
        *(uint4*)&kvv[r * 128 + cc * 16 + 8] = v1;
    }
    {   // dists -> f16, stride 40 halves
        float4 v = *(const float4*)&dist[(size_t)n * 1024 + t * 4];
        int kk = t >> 3, d0 = (t & 7) * 4;
        *(uint2*)&distsH[kk * LDDH + d0] = make_uint2(pack2h(v.x, v.y), pack2h(v.z, v.w));
    }
    if (t < 128) {   // seqs -> f16, stride 24 halves
        float4 v = *(const float4*)&seq[(size_t)n * 512 + t * 4];
        int kk = t >> 2, s0 = (t & 3) * 4;
        *(uint2*)&seqsH[kk * LDSH + s0] = make_uint2(pack2h(v.x, v.y), pack2h(v.z, v.w));
    }
    __syncthreads();

    {   // logits: 64 v_dot2_f32_f16, operands already in registers / staged LDS
        float lg = 0.f;
        lg = dot_h2(mk0.x, qv6.x, lg); lg = dot_h2(mk0.y, qv6.y, lg);
        lg = dot_h2(mk0.z, qv6.z, lg); lg = dot_h2(mk0.w, qv6.w, lg);
        lg = dot_h2(mk1.x, qv7.x, lg); lg = dot_h2(mk1.y, qv7.y, lg);
        lg = dot_h2(mk1.z, qv7.z, lg); lg = dot_h2(mk1.w, qv7.w, lg);
        const uint4* drp = (const uint4*)&distsH[k * LDDH];
        {
            uint4 a = drp[0];
            lg = dot_h2(a.x, qv0.x, lg); lg = dot_h2(a.y, qv0.y, lg);
            lg = dot_h2(a.z, qv0.z, lg); lg = dot_h2(a.w, qv0.w, lg);
            a = drp[1];
            lg = dot_h2(a.x, qv1.x, lg); lg = dot_h2(a.y, qv1.y, lg);
            lg = dot_h2(a.z, qv1.z, lg); lg = dot_h2(a.w, qv1.w, lg);
            a = drp[2];
            lg = dot_h2(a.x, qv2.x, lg); lg = dot_h2(a.y, qv2.y, lg);
            lg = dot_h2(a.z, qv2.z, lg); lg = dot_h2(a.w, qv2.w, lg);
            a = drp[3];
            lg = dot_h2(a.x, qv3.x, lg); lg = dot_h2(a.y, qv3.y, lg);
            lg = dot_h2(a.z, qv3.z, lg); lg = dot_h2(a.w, qv3.w, lg);
        }
        const uint4* srp = (const uint4*)&seqsH[k * LDSH];
        {
            uint4 a = srp[0];
            lg = dot_h2(a.x, qv4.x, lg); lg = dot_h2(a.y, qv4.y, lg);
            lg = dot_h2(a.z, qv4.z, lg); lg = dot_h2(a.w, qv4.w, lg);
            a = srp[1];
            lg = dot_h2(a.x, qv5.x, lg); lg = dot_h2(a.y, qv5.y, lg);
            lg = dot_h2(a.z, qv5.z, lg); lg = dot_h2(a.w, qv5.w, lg);
        }
        lg *= 0.25f;   // 1/sqrt(ADIM=16)
        // logits are bounded (|lg| << 88): exp is f32-safe without max subtraction
        float e = __expf(lg);
        float sum = e;
#pragma unroll
        for (int off = 16; off; off >>= 1) sum += __shfl_xor(sum, off);
        attn_s[h * 36 + k] = e / sum;
    }
    __syncthreads();

    // single-pass epilogue: 2 output cols/thread, packed b32 LDS reads + v_fma_mix.
    // Branches align to wave boundaries.
    ushort* od = &ovec[(size_t)n * 512];
    if (t < 64) {               // o: cols 2t,2t+1 of msgv part
        const int hh = t >> 3;
        const float* ap = &attn_s[hh * 36];
        const ushort* src = &kvv[2 * t];
        float a0 = 0.f, a1 = 0.f;
#pragma unroll
        for (int i8 = 0; i8 < 8; ++i8) {
            float4 av = *(const float4*)&ap[i8 * 4];
            fma2(av.x, *(const uint*)&src[(i8 * 4 + 0) * 128], a0, a1);
            fma2(av.y, *(const uint*)&src[(i8 * 4 + 1) * 128], a0, a1);
            fma2(av.z, *(const uint*)&src[(i8 * 4 + 2) * 128], a0, a1);
            fma2(av.w, *(const uint*)&src[(i8 * 4 + 3) * 128], a0, a1);
        }
        *(uint*)&od[2 * t] = pack2h(a0, a1);
    } else if (t < 192) {       // wd: head hh, dist dims d0,d0+1
        const int i = t - 64;
        const int hh = i >> 4, d0 = (i & 15) * 2;
        const float* ap = &attn_s[hh * 36];
        const ushort* src = &distsH[d0];
        float a0 = 0.f, a1 = 0.f;
#pragma unroll
        for (int i8 = 0; i8 < 8; ++i8) {
            float4 av = *(const float4*)&ap[i8 * 4];
            fma2(av.x, *(const uint*)&src[(i8 * 4 + 0) * LDDH], a0, a1);
            fma2(av.y, *(const uint*)&src[(i8 * 4 + 1) * LDDH], a0, a1);
            fma2(av.z, *(const uint*)&src[(i8 * 4 + 2) * LDDH], a0, a1);
            fma2(av.w, *(const uint*)&src[(i8 * 4 + 3) * LDDH], a0, a1);
        }
        *(uint*)&od[128 + hh * 32 + d0] = pack2h(a0, a1);
    } else {                    // ws: head hh, seq dims s0,s0+1
        const int i = t - 192;
        const int hh = i >> 3, s0 = (i & 7) * 2;
        const float* ap = &attn_s[hh * 36];
        const ushort* src = &seqsH[s0];
        float a0 = 0.f, a1 = 0.f;
#pragma unroll
        for (int i8 = 0; i8 < 8; ++i8) {
            float4 av = *(const float4*)&ap[i8 * 4];
            fma2(av.x, *(const uint*)&src[(i8 * 4 + 0) * LDSH], a0, a1);
            fma2(av.y, *(const uint*)&src[(i8 * 4 + 1) * LDSH], a0, a1);
            fma2(av.z, *(const uint*)&src[(i8 * 4 + 2) * LDSH], a0, a1);
            fma2(av.w, *(const uint*)&src[(i8 * 4 + 3) * LDSH], a0, a1);
        }
        *(uint*)&od[384 + hh * 16 + s0] = pack2h(a0, a1);
    }
}

// ================= final: out = features + ovec(f16) @ BigW + cvec =================
__global__ __launch_bounds__(256) void final_kernel(
    const ushort* __restrict__ ovec, const float* __restrict__ BigW,
    const float* __restrict__ cvec, const float* __restrict__ features,
    float* __restrict__ out)
{
    __shared__ __align__(16) float bufA[TM * LDA];
    const int t = threadIdx.x;
    const int node0 = blockIdx.x * TM;
    const int m0 = (t >> 5) * 4;
    const int c0 = (t & 31) * 4;
    float acc[4][4];
#pragma unroll
    for (int mm = 0; mm < 4; ++mm)
#pragma unroll
        for (int cc = 0; cc < 4; ++cc) acc[mm][cc] = 0.f;

    for (int ck = 0; ck < 4; ++ck) {
        __syncthreads();
#pragma unroll
        for (int r = 0; r < 4; ++r) {
            int fid = t + 256 * r;
            int row = fid >> 5, c4 = (fid & 31) * 4;
            uint2 u = *(const uint2*)&ovec[(size_t)(node0 + row) * 512 + ck * 128 + c4];
            float2 a = h2f2(u.x), b = h2f2(u.y);
            *(float4*)&bufA[row * LDA + c4] = make_float4(a.x, a.y, b.x, b.y);
        }
        __syncthreads();
        const float* Wc = BigW + ck * 128 * 128;
#pragma unroll 4
        for (int ic = 0; ic < 32; ++ic) {
            float a[4][4];
#pragma unroll
            for (int mm = 0; mm < 4; ++mm) {
                float4 av = *(const float4*)&bufA[(m0 + mm) * LDA + ic * 4];
                a[mm][0] = av.x; a[mm][1] = av.y; a[mm][2] = av.z; a[mm][3] = av.w;
            }
            float w[4][4];
#pragma unroll
            for (int ii = 0; ii < 4; ++ii) {
                float4 wv = *(const float4*)&Wc[(ic * 4 + ii) * 128 + c0];
                w[ii][0] = wv.x; w[ii][1] = wv.y; w[ii][2] = wv.z; w[ii][3] = wv.w;
            }
#pragma unroll
            for (int mm = 0; mm < 4; ++mm)
#pragma unroll
                for (int ii = 0; ii < 4; ++ii) {
                    float av = a[mm][ii];
#pragma unroll
                    for (int cc = 0; cc < 4; ++cc)
                        acc[mm][cc] = fmaf(av, w[ii][cc], acc[mm][cc]);
                }
        }
    }
    float4 cv = *(const float4*)&cvec[c0];
#pragma unroll
    for (int mm = 0; mm < 4; ++mm) {
        float4 f = *(const float4*)&features[(size_t)(node0 + m0 + mm) * 128 + c0];
        *(float4*)&out[(size_t)(node0 + m0 + mm) * 128 + c0] =
            make_float4(acc[mm][0] + f.x + cv.x, acc[mm][1] + f.y + cv.y,
                        acc[mm][2] + f.z + cv.z, acc[mm][3] + f.w + cv.w);
    }
}

extern "C" void kernel_launch(void* const* d_in, const int* in_sizes, int n_in,
                              void* d_out, int out_size, void* d_ws, size_t ws_size,
                              hipStream_t stream)
{
    const float* features = (const float*)d_in[0];
    const float* dist     = (const float*)d_in[1];
    const float* seq      = (const float*)d_in[2];
    const float* enc      = (const float*)d_in[3];
    const int*   idx      = (const int*)d_in[4];
    const float* W1 = (const float*)d_in[5];
    const float* b1 = (const float*)d_in[6];
    const float* W2 = (const float*)d_in[7];
    const float* b2 = (const float*)d_in[8];
    const float* W3 = (const float*)d_in[9];
    const float* b3 = (const float*)d_in[10];
    const float* Wq = (const float*)d_in[11];
    const float* bq = (const float*)d_in[12];
    const float* Wk = (const float*)d_in[13];
    // d_in[14] = bk: dropped (softmax-invariant)
    const float* Wv = (const float*)d_in[15];
    const float* bv = (const float*)d_in[16];
    const float* Wo = (const float*)d_in[17];
    const float* bo = (const float*)d_in[18];
    float* out = (float*)d_out;

    // Workspace: kv 8 | qext 16 | ovec 16 | BigW 256K | cvec | wpack 192K  (~40.5 MB)
    char* ws = (char*)d_ws;
    ushort* kv    = (ushort*)ws;
    ushort* qext  = (ushort*)(ws + ((size_t)8  << 20));
    ushort* ovec  = (ushort*)(ws + ((size_t)24 << 20));
    float*  BigW  = (float*)(ws + ((size_t)40 << 20));
    float*  cvec  = (float*)(ws + ((size_t)40 << 20) + 262144);
    ushort* wpack = (ushort*)(ws + ((size_t)40 << 20) + 262144 + 512);

    prep_kernel<<<704, 128, 0, stream>>>(Wv, Wo, bv, bo, W1, W2, W3, Wq, Wk,
                                         BigW, cvec, wpack);
    phaseA_kernel<<<NN / TM, 256, 0, stream>>>(
        features, enc, b1, b2, b3, bq, Wk, wpack, qext, kv);
    attn_kernel<<<NN, 256, 0, stream>>>(qext, kv, dist, seq, idx, ovec);
    final_kernel<<<NN / TM, 256, 0, stream>>>(ovec, BigW, cvec, features, out);
}

// Round 10
// 263.097 us; speedup vs baseline: 1.0352x; 1.0279x over previous
//
#include <hip/hip_runtime.h>
#include <hip/hip_fp16.h>
#include <math.h>

#define NN 16384
#define TM 32
#define LDA 132   // f32 LDS row stride (128 + 4 pad)
#define LDH 136   // f16 LDS row stride (128 + 8 pad, keeps 16B alignment)
#define LDDH 40   // dists f16 stride (80 B rows, 16B-aligned)
#define LDSH 24   // seqs f16 stride (48 B rows, 16B-aligned)

typedef unsigned int uint;
typedef unsigned short ushort;
typedef _Float16 half8 __attribute__((ext_vector_type(8)));
typedef _Float16 half2v __attribute__((ext_vector_type(2)));
typedef float floatx4 __attribute__((ext_vector_type(4)));

__device__ __forceinline__ uint pack2h(float a, float b) {
    _Float16 ha = (_Float16)a, hb = (_Float16)b;
    ushort ua = *(ushort*)&ha, ub = *(ushort*)&hb;
    return (uint)ua | ((uint)ub << 16);
}
__device__ __forceinline__ float2 h2f2(uint u) {
    __half2 h = *(__half2*)&u;
    return __half22float2(h);
}
// packed f16 pair dot with f32 accumulate — single v_dot2_f32_f16
__device__ __forceinline__ float dot_h2(uint a, uint b, float acc) {
    half2v ha = *(half2v*)&a, hb = *(half2v*)&b;
    return __builtin_amdgcn_fdot2(ha, hb, acc, false);
}
// f32 scalar × packed-f16 pair -> two f32 accumulators (2× v_fma_mix_f32)
__device__ __forceinline__ void fma2(float a, uint v, float& acc0, float& acc1) {
    __half2 h = *(__half2*)&v;
    acc0 += a * (float)__low2half(h);
    acc1 += a * (float)__high2half(h);
}

// ================= phaseA: MFMA f16 fused 6-GEMM chain + qext =================
// A-frag: A[m=lane&15][k=quad*8+j]  B-frag: B[k=quad*8+j][n=lane&15]
// C/D: col=lane&15, row=quad*4+reg (m89-verified).

struct Acc4 { floatx4 a[4]; };

template<bool RELUA>
__device__ __forceinline__ Acc4 mfma_gemm(const ushort* Ab, const half8* wp, int lane, int w)
{
    const int m  = (w & 1) * 16 + (lane & 15);
    const int kq = (lane >> 4) * 8;
    const int cg = w >> 1;
    half8 afr[4];
#pragma unroll
    for (int ks = 0; ks < 4; ++ks) {
        afr[ks] = *(const half8*)&Ab[m * LDH + ks * 32 + kq];
        if (RELUA) {
#pragma unroll
            for (int j = 0; j < 8; ++j)
                afr[ks][j] = afr[ks][j] > (_Float16)0.f ? afr[ks][j] : (_Float16)0.f;
        }
    }
    Acc4 r;
#pragma unroll
    for (int ct = 0; ct < 4; ++ct) {
        const int CT = cg * 4 + ct;
        floatx4 acc = {0.f, 0.f, 0.f, 0.f};
#pragma unroll
        for (int ks = 0; ks < 4; ++ks) {
            half8 bfr = wp[(CT * 4 + ks) * 64 + lane];
            acc = __builtin_amdgcn_mfma_f32_16x16x32_f16(afr[ks], bfr, acc, 0, 0, 0);
        }
        r.a[ct] = acc;
    }
    return r;
}

template<bool HAS_BIAS, bool RELU, bool HAS_ENC, bool F16OUT>
__device__ __forceinline__ void epilogue(const Acc4& ac, const float* __restrict__ bias,
    const float* __restrict__ enc, ushort* dst16, float* dst32,
    int node0, int lane, int w)
{
    const int row0 = (w & 1) * 16 + ((lane >> 4) << 2);
    const int cg = w >> 1;
#pragma unroll
    for (int ct = 0; ct < 4; ++ct) {
        const int col = (cg * 4 + ct) * 16 + (lane & 15);
        float bb = HAS_BIAS ? bias[col] : 0.f;
#pragma unroll
        for (int r = 0; r < 4; ++r) {
            float x = ac.a[ct][r] + bb;
            if (RELU) x = fmaxf(x, 0.f);
            if (HAS_ENC) x += enc[(size_t)(node0 + row0 + r) * 128 + col];
            if (F16OUT) {
                _Float16 h = (_Float16)x;
                dst16[(row0 + r) * LDH + col] = *(ushort*)&h;
            } else {
                dst32[(row0 + r) * LDA + col] = x;
            }
        }
    }
}

__global__ __launch_bounds__(256) void phaseA_kernel(
    const float* __restrict__ features, const float* __restrict__ enc,
    const float* __restrict__ b1, const float* __restrict__ b2,
    const float* __restrict__ b3, const float* __restrict__ bq,
    const float* __restrict__ Wk, const ushort* __restrict__ wpack,
    ushort* __restrict__ qext, ushort* __restrict__ kv)
{
    __shared__ __align__(16) ushort bufA[TM * LDH];
    __shared__ __align__(16) ushort bufB[TM * LDH];
    __shared__ __align__(16) float  qstage[TM * LDA];
    __shared__ __align__(16) float  wk[48 * 128];
    ushort* vstage = (ushort*)qstage;

    const int t = threadIdx.x;
    const int lane = t & 63, w = t >> 6;
    const int node0 = blockIdx.x * TM;

    const half8* wpQ = (const half8*)(wpack + 0 * 16384);
    const half8* wp1 = (const half8*)(wpack + 1 * 16384);
    const half8* wp2 = (const half8*)(wpack + 2 * 16384);
    const half8* wp3 = (const half8*)(wpack + 3 * 16384);
    const half8* wpK = (const half8*)(wpack + 4 * 16384);
    const half8* wpV = (const half8*)(wpack + 5 * 16384);

#pragma unroll
    for (int r = 0; r < 4; ++r) {
        int fid = t + 256 * r;
        int row = fid >> 5, c4 = (fid & 31) * 4;
        float4 v = *(const float4*)&features[(size_t)(node0 + row) * 128 + c4];
        uint2 h = make_uint2(pack2h(v.x, v.y), pack2h(v.z, v.w));
        *(uint2*)&bufA[row * LDH + c4] = h;
    }
#pragma unroll
    for (int r = 0; r < 6; ++r) {
        int fid = t + 256 * r;
        *(float4*)&wk[fid * 4] = *(const float4*)&Wk[128 * 128 + fid * 4];
    }
    __syncthreads();

    Acc4 aQ = mfma_gemm<false>(bufA, wpQ, lane, w);          // q = F@Wq
    Acc4 a1 = mfma_gemm<true >(bufA, wp1, lane, w);          // relu(F)@W1
    epilogue<true, false, false, false>(aQ, bq, nullptr, nullptr, qstage, node0, lane, w);
    epilogue<true, true,  false, true >(a1, b1, nullptr, bufB, nullptr, node0, lane, w);
    __syncthreads();

    Acc4 a2 = mfma_gemm<false>(bufB, wp2, lane, w);          // h1@W2

    // fused qext: per (node m, head hh): 48 ext dots + q copy, f16 out
    {
        const int m = t >> 3, hh = t & 7;
        float q[16];
#pragma unroll
        for (int jj = 0; jj < 4; ++jj)
            *(float4*)&q[jj * 4] = *(const float4*)&qstage[m * LDA + hh * 16 + jj * 4];
        ushort* dst = &qext[(size_t)(node0 + m) * 512 + hh * 64];
#pragma unroll
        for (int x0 = 0; x0 < 48; x0 += 8) {
            float res[8];
#pragma unroll
            for (int xx = 0; xx < 8; ++xx) {
                const float* wr = &wk[(x0 + xx) * 128 + hh * 16];
                float s = 0.f;
#pragma unroll
                for (int jj = 0; jj < 4; ++jj) {
                    float4 wv = *(const float4*)&wr[jj * 4];
                    s += q[jj*4+0]*wv.x + q[jj*4+1]*wv.y + q[jj*4+2]*wv.z + q[jj*4+3]*wv.w;
                }
                res[xx] = s;
            }
            *(uint4*)&dst[x0] = make_uint4(pack2h(res[0], res[1]), pack2h(res[2], res[3]),
                                           pack2h(res[4], res[5]), pack2h(res[6], res[7]));
        }
        *(uint4*)&dst[48] = make_uint4(pack2h(q[0], q[1]),  pack2h(q[2], q[3]),
                                       pack2h(q[4], q[5]),  pack2h(q[6], q[7]));
        *(uint4*)&dst[56] = make_uint4(pack2h(q[8], q[9]),  pack2h(q[10], q[11]),
                                       pack2h(q[12], q[13]), pack2h(q[14], q[15]));
    }
    epilogue<true, true, false, true>(a2, b2, nullptr, bufA, nullptr, node0, lane, w);
    __syncthreads();

    Acc4 a3 = mfma_gemm<false>(bufA, wp3, lane, w);          // h2@W3
    epilogue<true, true, true, true>(a3, b3, enc, bufB, nullptr, node0, lane, w);  // msg
    __syncthreads();

    Acc4 aK = mfma_gemm<false>(bufB, wpK, lane, w);          // msg@Wk[:128]
    Acc4 aV = mfma_gemm<false>(bufB, wpV, lane, w);          // msg@Wv[:128]
    epilogue<false, false, false, true>(aK, nullptr, nullptr, bufA,   nullptr, node0, lane, w);
    epilogue<false, false, false, true>(aV, nullptr, nullptr, vstage, nullptr, node0, lane, w);
    __syncthreads();

    {
        int row = t >> 3, c16 = (t & 7) * 16;
        size_t kbase = (size_t)(node0 + row) * 256;
        *(uint4*)&kv[kbase + c16]           = *(const uint4*)&bufA[row * LDH + c16];
        *(uint4*)&kv[kbase + c16 + 8]       = *(const uint4*)&bufA[row * LDH + c16 + 8];
        *(uint4*)&kv[kbase + 128 + c16]     = *(const uint4*)&vstage[row * LDH + c16];
        *(uint4*)&kv[kbase + 128 + c16 + 8] = *(const uint4*)&vstage[row * LDH + c16 + 8];
    }
}

// ===== merged prep: BigW/cvec (blocks 0..511) + wpack (blocks 512..703) =====
__global__ void prep_kernel(
    const float* __restrict__ Wv, const float* __restrict__ Wo,
    const float* __restrict__ bv, const float* __restrict__ bo,
    const float* __restrict__ W1, const float* __restrict__ W2,
    const float* __restrict__ W3, const float* __restrict__ Wq,
    const float* __restrict__ Wk,
    float* __restrict__ BigW, float* __restrict__ cvec,
    ushort* __restrict__ wpack)
{
    const int r = blockIdx.x;
    const int c = threadIdx.x;
    if (r < 512) {
        float s = 0.f;
        if (r < 128) {
            s = Wo[r * 128 + c];
        } else if (r < 384) {
            int x = r - 128; int hh = x >> 5, d = x & 31;
#pragma unroll
            for (int a = 0; a < 16; ++a)
                s += Wv[(128 + d) * 128 + hh * 16 + a] * Wo[(hh * 16 + a) * 128 + c];
        } else {
            int x = r - 384; int hh = x >> 4, ss = x & 15;
#pragma unroll
            for (int a = 0; a < 16; ++a)
                s += Wv[(160 + ss) * 128 + hh * 16 + a] * Wo[(hh * 16 + a) * 128 + c];
        }
        BigW[r * 128 + c] = s;
        if (r == 0) {
            float cv = bo[c];
            for (int jj = 0; jj < 128; ++jj) cv += bv[jj] * Wo[jj * 128 + c];
            cvec[c] = cv;
        }
    } else {
        if (c >= 64) return;
        const int bb = r - 512;          // 0..191
        const int g = bb >> 5;
        const int rem = bb & 31;
        const int CT = rem >> 2, ks = rem & 3;
        const float* W = (g == 0) ? Wq : (g == 1) ? W1 : (g == 2) ? W2
                       : (g == 3) ? W3 : (g == 4) ? Wk : Wv;
        const int n = CT * 16 + (c & 15);
        const int k0 = ks * 32 + (c >> 4) * 8;
        ushort out[8];
#pragma unroll
        for (int j = 0; j < 8; ++j) {
            _Float16 h = (_Float16)W[(k0 + j) * 128 + n];
            out[j] = *(ushort*)&h;
        }
        *(uint4*)&wpack[(size_t)(((g * 8 + CT) * 4 + ks) * 64 + c) * 8] = *(uint4*)out;
    }
}

// ==== attn: R7 structure (qeH LDS, fdot2) + full occupancy + max-free softmax ====
__global__ __launch_bounds__(256, 8) void attn_kernel(
    const ushort* __restrict__ qext, const ushort* __restrict__ kv,
    const float* __restrict__ dist, const float* __restrict__ seq,
    const int* __restrict__ idx, ushort* __restrict__ ovec)
{
    __shared__ __align__(16) ushort distsH[32 * LDDH];
    __shared__ __align__(16) ushort seqsH[32 * LDSH];
    __shared__ __align__(16) ushort qeH[512];       // [h*64 + {48 ext | 16 q}]
    __shared__ __align__(16) float attn_s[8 * 36];  // stride 36 -> conflict-free bcast
    __shared__ __align__(16) ushort kvv[32 * 128];

    const int t = threadIdx.x;
    const int n = blockIdx.x;
    const int h = t >> 5, k = t & 31;

    int j = idx[n * 32 + k];
    const uint4* mkp = (const uint4*)(kv + (size_t)j * 256 + h * 16);
    uint4 mk0 = mkp[0], mk1 = mkp[1];

    {   // msgv half -> LDS rows (8 threads/row)
        int r = t >> 3, cc = t & 7;
        int j2 = idx[n * 32 + r];
        const uint4* vp = (const uint4*)(kv + (size_t)j2 * 256 + 128 + cc * 16);
        uint4 v0 = vp[0], v1 = vp[1];
        *(uint4*)&kvv[r * 128 + cc * 16] = v0;
        *(uint4*)&kvv[r * 128 + cc * 16 + 8] = v1;
    }
    {   // dists -> f16, stride 40 halves
        float4 v = *(const float4*)&dist[(size_t)n * 1024 + t * 4];
        int kk = t >> 3, d0 = (t & 7) * 4;
        *(uint2*)&distsH[kk * LDDH + d0] = make_uint2(pack2h(v.x, v.y), pack2h(v.z, v.w));
    }
    if (t < 128) {   // seqs -> f16, stride 24 halves
        float4 v = *(const float4*)&seq[(size_t)n * 512 + t * 4];
        int kk = t >> 2, s0 = (t & 3) * 4;
        *(uint2*)&seqsH[kk * LDSH + s0] = make_uint2(pack2h(v.x, v.y), pack2h(v.z, v.w));
    }
    if (t < 64)      // qext stays f16 — raw copy, no unpack
        *(uint4*)&qeH[t * 8] = *(const uint4*)&qext[(size_t)n * 512 + t * 8];
    __syncthreads();

    {   // logits: 64 v_dot2_f32_f16 + 14 b128 LDS reads; max-free softmax
        float lg = 0.f;
        const uint4* qhp = (const uint4*)&qeH[h * 64 + 48];
        uint4 q0 = qhp[0], q1 = qhp[1];
        lg = dot_h2(mk0.x, q0.x, lg); lg = dot_h2(mk0.y, q0.y, lg);
        lg = dot_h2(mk0.z, q0.z, lg); lg = dot_h2(mk0.w, q0.w, lg);
        lg = dot_h2(mk1.x, q1.x, lg); lg = dot_h2(mk1.y, q1.y, lg);
        lg = dot_h2(mk1.z, q1.z, lg); lg = dot_h2(mk1.w, q1.w, lg);
        const uint4* drp = (const uint4*)&distsH[k * LDDH];
        const uint4* qdp = (const uint4*)&qeH[h * 64];
#pragma unroll
        for (int i = 0; i < 4; ++i) {
            uint4 a = drp[i], b = qdp[i];
            lg = dot_h2(a.x, b.x, lg); lg = dot_h2(a.y, b.y, lg);
            lg = dot_h2(a.z, b.z, lg); lg = dot_h2(a.w, b.w, lg);
        }
        const uint4* srp = (const uint4*)&seqsH[k * LDSH];
        const uint4* qsp = (const uint4*)&qeH[h * 64 + 32];
#pragma unroll
        for (int i = 0; i < 2; ++i) {
            uint4 a = srp[i], b = qsp[i];
            lg = dot_h2(a.x, b.x, lg); lg = dot_h2(a.y, b.y, lg);
            lg = dot_h2(a.z, b.z, lg); lg = dot_h2(a.w, b.w, lg);
        }
        lg *= 0.25f;   // 1/sqrt(ADIM=16)
        // logits bounded (|lg| << 88): f32 exp safe without max subtraction
        float e = __expf(lg);
        float sum = e;
#pragma unroll
        for (int off = 16; off; off >>= 1) sum += __shfl_xor(sum, off);
        attn_s[h * 36 + k] = e / sum;
    }
    __syncthreads();

    // single-pass epilogue: 2 output cols/thread, packed b32 LDS reads + v_fma_mix.
    // Branches align to wave boundaries.
    ushort* od = &ovec[(size_t)n * 512];
    if (t < 64) {               // o: cols 2t,2t+1 of msgv part
        const int hh = t >> 3;
        const float* ap = &attn_s[hh * 36];
        const ushort* src = &kvv[2 * t];
        float a0 = 0.f, a1 = 0.f;
#pragma unroll
        for (int i8 = 0; i8 < 8; ++i8) {
            float4 av = *(const float4*)&ap[i8 * 4];
            fma2(av.x, *(const uint*)&src[(i8 * 4 + 0) * 128], a0, a1);
            fma2(av.y, *(const uint*)&src[(i8 * 4 + 1) * 128], a0, a1);
            fma2(av.z, *(const uint*)&src[(i8 * 4 + 2) * 128], a0, a1);
            fma2(av.w, *(const uint*)&src[(i8 * 4 + 3) * 128], a0, a1);
        }
        *(uint*)&od[2 * t] = pack2h(a0, a1);
    } else if (t < 192) {       // wd: head hh, dist dims d0,d0+1
        const int i = t - 64;
        const int hh = i >> 4, d0 = (i & 15) * 2;
        const float* ap = &attn_s[hh * 36];
        const ushort* src = &distsH[d0];
        float a0 = 0.f, a1 = 0.f;
#pragma unroll
        for (int i8 = 0; i8 < 8; ++i8) {
            float4 av = *(const float4*)&ap[i8 * 4];
            fma2(av.x, *(const uint*)&src[(i8 * 4 + 0) * LDDH], a0, a1);
            fma2(av.y, *(const uint*)&src[(i8 * 4 + 1) * LDDH], a0, a1);
            fma2(av.z, *(const uint*)&src[(i8 * 4 + 2) * LDDH], a0, a1);
            fma2(av.w, *(const uint*)&src[(i8 * 4 + 3) * LDDH], a0, a1);
        }
        *(uint*)&od[128 + hh * 32 + d0] = pack2h(a0, a1);
    } else {                    // ws: head hh, seq dims s0,s0+1
        const int i = t - 192;
        const int hh = i >> 3, s0 = (i & 7) * 2;
        const float* ap = &attn_s[hh * 36];
        const ushort* src = &seqsH[s0];
        float a0 = 0.f, a1 = 0.f;
#pragma unroll
        for (int i8 = 0; i8 < 8; ++i8) {
            float4 av = *(const float4*)&ap[i8 * 4];
            fma2(av.x, *(const uint*)&src[(i8 * 4 + 0) * LDSH], a0, a1);
            fma2(av.y, *(const uint*)&src[(i8 * 4 + 1) * LDSH], a0, a1);
            fma2(av.z, *(const uint*)&src[(i8 * 4 + 2) * LDSH], a0, a1);
            fma2(av.w, *(const uint*)&src[(i8 * 4 + 3) * LDSH], a0, a1);
        }
        *(uint*)&od[384 + hh * 16 + s0] = pack2h(a0, a1);
    }
}

// ================= final: out = features + ovec(f16) @ BigW + cvec =================
__global__ __launch_bounds__(256) void final_kernel(
    const ushort* __restrict__ ovec, const float* __restrict__ BigW,
    const float* __restrict__ cvec, const float* __restrict__ features,
    float* __restrict__ out)
{
    __shared__ __align__(16) float bufA[TM * LDA];
    const int t = threadIdx.x;
    const int node0 = blockIdx.x * TM;
    const int m0 = (t >> 5) * 4;
    const int c0 = (t & 31) * 4;
    float acc[4][4];
#pragma unroll
    for (int mm = 0; mm < 4; ++mm)
#pragma unroll
        for (int cc = 0; cc < 4; ++cc) acc[mm][cc] = 0.f;

    for (int ck = 0; ck < 4; ++ck) {
        __syncthreads();
#pragma unroll
        for (int r = 0; r < 4; ++r) {
            int fid = t + 256 * r;
            int row = fid >> 5, c4 = (fid & 31) * 4;
            uint2 u = *(const uint2*)&ovec[(size_t)(node0 + row) * 512 + ck * 128 + c4];
            float2 a = h2f2(u.x), b = h2f2(u.y);
            *(float4*)&bufA[row * LDA + c4] = make_float4(a.x, a.y, b.x, b.y);
        }
        __syncthreads();
        const float* Wc = BigW + ck * 128 * 128;
#pragma unroll 4
        for (int ic = 0; ic < 32; ++ic) {
            float a[4][4];
#pragma unroll
            for (int mm = 0; mm < 4; ++mm) {
                float4 av = *(const float4*)&bufA[(m0 + mm) * LDA + ic * 4];
                a[mm][0] = av.x; a[mm][1] = av.y; a[mm][2] = av.z; a[mm][3] = av.w;
            }
            float w[4][4];
#pragma unroll
            for (int ii = 0; ii < 4; ++ii) {
                float4 wv = *(const float4*)&Wc[(ic * 4 + ii) * 128 + c0];
                w[ii][0] = wv.x; w[ii][1] = wv.y; w[ii][2] = wv.z; w[ii][3] = wv.w;
            }
#pragma unroll
            for (int mm = 0; mm < 4; ++mm)
#pragma unroll
                for (int ii = 0; ii < 4; ++ii) {
                    float av = a[mm][ii];
#pragma unroll
                    for (int cc = 0; cc < 4; ++cc)
                        acc[mm][cc] = fmaf(av, w[ii][cc], acc[mm][cc]);
                }
        }
    }
    float4 cv = *(const float4*)&cvec[c0];
#pragma unroll
    for (int mm = 0; mm < 4; ++mm) {
        float4 f = *(const float4*)&features[(size_t)(node0 + m0 + mm) * 128 + c0];
        *(float4*)&out[(size_t)(node0 + m0 + mm) * 128 + c0] =
            make_float4(acc[mm][0] + f.x + cv.x, acc[mm][1] + f.y + cv.y,
                        acc[mm][2] + f.z + cv.z, acc[mm][3] + f.w + cv.w);
    }
}

extern "C" void kernel_launch(void* const* d_in, const int* in_sizes, int n_in,
                              void* d_out, int out_size, void* d_ws, size_t ws_size,
                              hipStream_t stream)
{
    const float* features = (const float*)d_in[0];
    const float* dist     = (const float*)d_in[1];
    const float* seq      = (const float*)d_in[2];
    const float* enc      = (const float*)d_in[3];
    const int*   idx      = (const int*)d_in[4];
    const float* W1 = (const float*)d_in[5];
    const float* b1 = (const float*)d_in[6];
    const float* W2 = (const float*)d_in[7];
    const float* b2 = (const float*)d_in[8];
    const float* W3 = (const float*)d_in[9];
    const float* b3 = (const float*)d_in[10];
    const float* Wq = (const float*)d_in[11];
    const float* bq = (const float*)d_in[12];
    const float* Wk = (const float*)d_in[13];
    // d_in[14] = bk: dropped (softmax-invariant)
    const float* Wv = (const float*)d_in[15];
    const float* bv = (const float*)d_in[16];
    const float* Wo = (const float*)d_in[17];
    const float* bo = (const float*)d_in[18];
    float* out = (float*)d_out;

    // Workspace: kv 8 | qext 16 | ovec 16 | BigW 256K | cvec | wpack 192K  (~40.5 MB)
    char* ws = (char*)d_ws;
    ushort* kv    = (ushort*)ws;
    ushort* qext  = (ushort*)(ws + ((size_t)8  << 20));
    ushort* ovec  = (ushort*)(ws + ((size_t)24 << 20));
    float*  BigW  = (float*)(ws + ((size_t)40 << 20));
    float*  cvec  = (float*)(ws + ((size_t)40 << 20) + 262144);
    ushort* wpack = (ushort*)(ws + ((size_t)40 << 20) + 262144 + 512);

    prep_kernel<<<704, 128, 0, stream>>>(Wv, Wo, bv, bo, W1, W2, W3, Wq, Wk,
                                         BigW, cvec, wpack);
    phaseA_kernel<<<NN / TM, 256, 0, stream>>>(
        features, enc, b1, b2, b3, bq, Wk, wpack, qext, kv);
    attn_kernel<<<NN, 256, 0, stream>>>(qext, kv, dist, seq, idx, ovec);
    final_kernel<<<NN / TM, 256, 0, stream>>>(ovec, BigW, cvec, features, out);
}

// Round 12
// 255.105 us; speedup vs baseline: 1.0676x; 1.0313x over previous
//
#include <hip/hip_runtime.h>
#include <hip/hip_fp16.h>
#include <math.h>

#define NN 16384
#define TM 32
#define LDA 132   // f32 LDS row stride (128 + 4 pad)
#define LDH 136   // f16 LDS row stride (128 + 8 pad, keeps 16B alignment)
#define LDDH 40   // dists f16 stride (80 B rows, 16B-aligned)
#define LDSH 24   // seqs f16 stride (48 B rows, 16B-aligned)

typedef unsigned int uint;
typedef unsigned short ushort;
typedef _Float16 half8 __attribute__((ext_vector_type(8)));
typedef _Float16 half2v __attribute__((ext_vector_type(2)));
typedef float floatx4 __attribute__((ext_vector_type(4)));

__device__ __forceinline__ uint pack2h(float a, float b) {
    _Float16 ha = (_Float16)a, hb = (_Float16)b;
    ushort ua = *(ushort*)&ha, ub = *(ushort*)&hb;
    return (uint)ua | ((uint)ub << 16);
}
__device__ __forceinline__ float2 h2f2(uint u) {
    __half2 h = *(__half2*)&u;
    return __half22float2(h);
}
// packed f16 pair dot with f32 accumulate — single v_dot2_f32_f16
__device__ __forceinline__ float dot_h2(uint a, uint b, float acc) {
    half2v ha = *(half2v*)&a, hb = *(half2v*)&b;
    return __builtin_amdgcn_fdot2(ha, hb, acc, false);
}
// f32 scalar × packed-f16 pair -> two f32 accumulators (2× v_fma_mix_f32)
__device__ __forceinline__ void fma2(float a, uint v, float& acc0, float& acc1) {
    __half2 h = *(__half2*)&v;
    acc0 += a * (float)__low2half(h);
    acc1 += a * (float)__high2half(h);
}

// ================= phaseA: MFMA f16 fused 6-GEMM chain + qext =================
// A-frag: A[m=lane&15][k=quad*8+j]  B-frag: B[k=quad*8+j][n=lane&15]
// C/D: col=lane&15, row=quad*4+reg (m89-verified).

struct Acc4 { floatx4 a[4]; };

template<bool RELUA>
__device__ __forceinline__ Acc4 mfma_gemm(const ushort* Ab, const half8* wp, int lane, int w)
{
    const int m  = (w & 1) * 16 + (lane & 15);
    const int kq = (lane >> 4) * 8;
    const int cg = w >> 1;
    half8 afr[4];
#pragma unroll
    for (int ks = 0; ks < 4; ++ks) {
        afr[ks] = *(const half8*)&Ab[m * LDH + ks * 32 + kq];
        if (RELUA) {
#pragma unroll
            for (int j = 0; j < 8; ++j)
                afr[ks][j] = afr[ks][j] > (_Float16)0.f ? afr[ks][j] : (_Float16)0.f;
        }
    }
    Acc4 r;
#pragma unroll
    for (int ct = 0; ct < 4; ++ct) {
        const int CT = cg * 4 + ct;
        floatx4 acc = {0.f, 0.f, 0.f, 0.f};
#pragma unroll
        for (int ks = 0; ks < 4; ++ks) {
            half8 bfr = wp[(CT * 4 + ks) * 64 + lane];
            acc = __builtin_amdgcn_mfma_f32_16x16x32_f16(afr[ks], bfr, acc, 0, 0, 0);
        }
        r.a[ct] = acc;
    }
    return r;
}

template<bool HAS_BIAS, bool RELU, bool HAS_ENC, bool F16OUT>
__device__ __forceinline__ void epilogue(const Acc4& ac, const float* __restrict__ bias,
    const float* __restrict__ enc, ushort* dst16, float* dst32,
    int node0, int lane, int w)
{
    const int row0 = (w & 1) * 16 + ((lane >> 4) << 2);
    const int cg = w >> 1;
#pragma unroll
    for (int ct = 0; ct < 4; ++ct) {
        const int col = (cg * 4 + ct) * 16 + (lane & 15);
        float bb = HAS_BIAS ? bias[col] : 0.f;
#pragma unroll
        for (int r = 0; r < 4; ++r) {
            float x = ac.a[ct][r] + bb;
            if (RELU) x = fmaxf(x, 0.f);
            if (HAS_ENC) x += enc[(size_t)(node0 + row0 + r) * 128 + col];
            if (F16OUT) {
                _Float16 h = (_Float16)x;
                dst16[(row0 + r) * LDH + col] = *(ushort*)&h;
            } else {
                dst32[(row0 + r) * LDA + col] = x;
            }
        }
    }
}

// LDS 38,400 B -> 4 blocks/CU (was 58,880 -> 2). qstage/wk in f16.
__global__ __launch_bounds__(256, 4) void phaseA_kernel(
    const float* __restrict__ features, const float* __restrict__ enc,
    const float* __restrict__ b1, const float* __restrict__ b2,
    const float* __restrict__ b3, const float* __restrict__ bq,
    const float* __restrict__ Wk, const ushort* __restrict__ wpack,
    ushort* __restrict__ qext, ushort* __restrict__ kv)
{
    __shared__ __align__(16) ushort bufA[TM * LDH];
    __shared__ __align__(16) ushort bufB[TM * LDH];
    __shared__ __align__(16) ushort qstageH[TM * LDH];  // q f16; later V stage
    __shared__ __align__(16) ushort wkH[48 * 128];      // Wk_ext f16

    const int t = threadIdx.x;
    const int lane = t & 63, w = t >> 6;
    const int node0 = blockIdx.x * TM;

    const half8* wpQ = (const half8*)(wpack + 0 * 16384);
    const half8* wp1 = (const half8*)(wpack + 1 * 16384);
    const half8* wp2 = (const half8*)(wpack + 2 * 16384);
    const half8* wp3 = (const half8*)(wpack + 3 * 16384);
    const half8* wpK = (const half8*)(wpack + 4 * 16384);
    const half8* wpV = (const half8*)(wpack + 5 * 16384);

#pragma unroll
    for (int r = 0; r < 4; ++r) {
        int fid = t + 256 * r;
        int row = fid >> 5, c4 = (fid & 31) * 4;
        float4 v = *(const float4*)&features[(size_t)(node0 + row) * 128 + c4];
        uint2 h = make_uint2(pack2h(v.x, v.y), pack2h(v.z, v.w));
        *(uint2*)&bufA[row * LDH + c4] = h;
    }
#pragma unroll
    for (int r = 0; r < 6; ++r) {
        int fid = t + 256 * r;
        float4 v = *(const float4*)&Wk[128 * 128 + fid * 4];
        *(uint2*)&wkH[fid * 4] = make_uint2(pack2h(v.x, v.y), pack2h(v.z, v.w));
    }
    __syncthreads();

    Acc4 aQ = mfma_gemm<false>(bufA, wpQ, lane, w);          // q = F@Wq
    Acc4 a1 = mfma_gemm<true >(bufA, wp1, lane, w);          // relu(F)@W1
    epilogue<true, false, false, true>(aQ, bq, nullptr, qstageH, nullptr, node0, lane, w);
    epilogue<true, true,  false, true>(a1, b1, nullptr, bufB,    nullptr, node0, lane, w);
    __syncthreads();

    Acc4 a2 = mfma_gemm<false>(bufB, wp2, lane, w);          // h1@W2

    // fused qext: per (node m, head hh): 48 ext dots via fdot2 + q copy, f16
    {
        const int m = t >> 3, hh = t & 7;
        uint qu[8];
        *(uint4*)&qu[0] = *(const uint4*)&qstageH[m * LDH + hh * 16];
        *(uint4*)&qu[4] = *(const uint4*)&qstageH[m * LDH + hh * 16 + 8];
        ushort* dst = &qext[(size_t)(node0 + m) * 512 + hh * 64];
#pragma unroll
        for (int x0 = 0; x0 < 48; x0 += 8) {
            float res[8];
#pragma unroll
            for (int xx = 0; xx < 8; ++xx) {
                const ushort* wr = &wkH[(x0 + xx) * 128 + hh * 16];
                uint4 w0 = *(const uint4*)&wr[0];
                uint4 w1 = *(const uint4*)&wr[8];
                float s = 0.f;
                s = dot_h2(qu[0], w0.x, s); s = dot_h2(qu[1], w0.y, s);
                s = dot_h2(qu[2], w0.z, s); s = dot_h2(qu[3], w0.w, s);
                s = dot_h2(qu[4], w1.x, s); s = dot_h2(qu[5], w1.y, s);
                s = dot_h2(qu[6], w1.z, s); s = dot_h2(qu[7], w1.w, s);
                res[xx] = s;
            }
            *(uint4*)&dst[x0] = make_uint4(pack2h(res[0], res[1]), pack2h(res[2], res[3]),
                                           pack2h(res[4], res[5]), pack2h(res[6], res[7]));
        }
        *(uint4*)&dst[48] = *(const uint4*)&qu[0];
        *(uint4*)&dst[56] = *(const uint4*)&qu[4];
    }
    epilogue<true, true, false, true>(a2, b2, nullptr, bufA, nullptr, node0, lane, w);
    __syncthreads();

    Acc4 a3 = mfma_gemm<false>(bufA, wp3, lane, w);          // h2@W3
    epilogue<true, true, true, true>(a3, b3, enc, bufB, nullptr, node0, lane, w);  // msg
    __syncthreads();

    Acc4 aK = mfma_gemm<false>(bufB, wpK, lane, w);          // msg@Wk[:128]
    Acc4 aV = mfma_gemm<false>(bufB, wpV, lane, w);          // msg@Wv[:128]
    epilogue<false, false, false, true>(aK, nullptr, nullptr, bufA,    nullptr, node0, lane, w);
    epilogue<false, false, false, true>(aV, nullptr, nullptr, qstageH, nullptr, node0, lane, w);
    __syncthreads();

    {
        int row = t >> 3, c16 = (t & 7) * 16;
        size_t kbase = (size_t)(node0 + row) * 256;
        *(uint4*)&kv[kbase + c16]           = *(const uint4*)&bufA[row * LDH + c16];
        *(uint4*)&kv[kbase + c16 + 8]       = *(const uint4*)&bufA[row * LDH + c16 + 8];
        *(uint4*)&kv[kbase + 128 + c16]     = *(const uint4*)&qstageH[row * LDH + c16];
        *(uint4*)&kv[kbase + 128 + c16 + 8] = *(const uint4*)&qstageH[row * LDH + c16 + 8];
    }
}

// ===== merged prep: BigW/cvec (blocks 0..511) + wpack (blocks 512..703) =====
__global__ void prep_kernel(
    const float* __restrict__ Wv, const float* __restrict__ Wo,
    const float* __restrict__ bv, const float* __restrict__ bo,
    const float* __restrict__ W1, const float* __restrict__ W2,
    const float* __restrict__ W3, const float* __restrict__ Wq,
    const float* __restrict__ Wk,
    float* __restrict__ BigW, float* __restrict__ cvec,
    ushort* __restrict__ wpack)
{
    const int r = blockIdx.x;
    const int c = threadIdx.x;
    if (r < 512) {
        float s = 0.f;
        if (r < 128) {
            s = Wo[r * 128 + c];
        } else if (r < 384) {
            int x = r - 128; int hh = x >> 5, d = x & 31;
#pragma unroll
            for (int a = 0; a < 16; ++a)
                s += Wv[(128 + d) * 128 + hh * 16 + a] * Wo[(hh * 16 + a) * 128 + c];
        } else {
            int x = r - 384; int hh = x >> 4, ss = x & 15;
#pragma unroll
            for (int a = 0; a < 16; ++a)
                s += Wv[(160 + ss) * 128 + hh * 16 + a] * Wo[(hh * 16 + a) * 128 + c];
        }
        BigW[r * 128 + c] = s;
        if (r == 0) {
            float cv = bo[c];
            for (int jj = 0; jj < 128; ++jj) cv += bv[jj] * Wo[jj * 128 + c];
            cvec[c] = cv;
        }
    } else {
        if (c >= 64) return;
        const int bb = r - 512;          // 0..191
        const int g = bb >> 5;
        const int rem = bb & 31;
        const int CT = rem >> 2, ks = rem & 3;
        const float* W = (g == 0) ? Wq : (g == 1) ? W1 : (g == 2) ? W2
                       : (g == 3) ? W3 : (g == 4) ? Wk : Wv;
        const int n = CT * 16 + (c & 15);
        const int k0 = ks * 32 + (c >> 4) * 8;
        ushort out[8];
#pragma unroll
        for (int j = 0; j < 8; ++j) {
            _Float16 h = (_Float16)W[(k0 + j) * 128 + n];
            out[j] = *(ushort*)&h;
        }
        *(uint4*)&wpack[(size_t)(((g * 8 + CT) * 4 + ks) * 64 + c) * 8] = *(uint4*)out;
    }
}

// ==== attn: R10 (qeH LDS, fdot2, max-free softmax, full occupancy) — unchanged ====
__global__ __launch_bounds__(256, 8) void attn_kernel(
    const ushort* __restrict__ qext, const ushort* __restrict__ kv,
    const float* __restrict__ dist, const float* __restrict__ seq,
    const int* __restrict__ idx, ushort* __restrict__ ovec)
{
    __shared__ __align__(16) ushort distsH[32 * LDDH];
    __shared__ __align__(16) ushort seqsH[32 * LDSH];
    __shared__ __align__(16) ushort qeH[512];       // [h*64 + {48 ext | 16 q}]
    __shared__ __align__(16) float attn_s[8 * 36];  // stride 36 -> conflict-free bcast
    __shared__ __align__(16) ushort kvv[32 * 128];

    const int t = threadIdx.x;
    const int n = blockIdx.x;
    const int h = t >> 5, k = t & 31;

    int j = idx[n * 32 + k];
    const uint4* mkp = (const uint4*)(kv + (size_t)j * 256 + h * 16);
    uint4 mk0 = mkp[0], mk1 = mkp[1];

    {   // msgv half -> LDS rows (8 threads/row)
        int r = t >> 3, cc = t & 7;
        int j2 = idx[n * 32 + r];
        const uint4* vp = (const uint4*)(kv + (size_t)j2 * 256 + 128 + cc * 16);
        uint4 v0 = vp[0], v1 = vp[1];
        *(uint4*)&kvv[r * 128 + cc * 16] = v0;
        *(uint4*)&kvv[r * 128 + cc * 16 + 8] = v1;
    }
    {   // dists -> f16, stride 40 halves
        float4 v = *(const float4*)&dist[(size_t)n * 1024 + t * 4];
        int kk = t >> 3, d0 = (t & 7) * 4;
        *(uint2*)&distsH[kk * LDDH + d0] = make_uint2(pack2h(v.x, v.y), pack2h(v.z, v.w));
    }
    if (t < 128) {   // seqs -> f16, stride 24 halves
        float4 v = *(const float4*)&seq[(size_t)n * 512 + t * 4];
        int kk = t >> 2, s0 = (t & 3) * 4;
        *(uint2*)&seqsH[kk * LDSH + s0] = make_uint2(pack2h(v.x, v.y), pack2h(v.z, v.w));
    }
    if (t < 64)      // qext stays f16 — raw copy, no unpack
        *(uint4*)&qeH[t * 8] = *(const uint4*)&qext[(size_t)n * 512 + t * 8];
    __syncthreads();

    {   // logits: 64 v_dot2_f32_f16 + 14 b128 LDS reads; max-free softmax
        float lg = 0.f;
        const uint4* qhp = (const uint4*)&qeH[h * 64 + 48];
        uint4 q0 = qhp[0], q1 = qhp[1];
        lg = dot_h2(mk0.x, q0.x, lg); lg = dot_h2(mk0.y, q0.y, lg);
        lg = dot_h2(mk0.z, q0.z, lg); lg = dot_h2(mk0.w, q0.w, lg);
        lg = dot_h2(mk1.x, q1.x, lg); lg = dot_h2(mk1.y, q1.y, lg);
        lg = dot_h2(mk1.z, q1.z, lg); lg = dot_h2(mk1.w, q1.w, lg);
        const uint4* drp = (const uint4*)&distsH[k * LDDH];
        const uint4* qdp = (const uint4*)&qeH[h * 64];
#pragma unroll
        for (int i = 0; i < 4; ++i) {
            uint4 a = drp[i], b = qdp[i];
            lg = dot_h2(a.x, b.x, lg); lg = dot_h2(a.y, b.y, lg);
            lg = dot_h2(a.z, b.z, lg); lg = dot_h2(a.w, b.w, lg);
        }
        const uint4* srp = (const uint4*)&seqsH[k * LDSH];
        const uint4* qsp = (const uint4*)&qeH[h * 64 + 32];
#pragma unroll
        for (int i = 0; i < 2; ++i) {
            uint4 a = srp[i], b = qsp[i];
            lg = dot_h2(a.x, b.x, lg); lg = dot_h2(a.y, b.y, lg);
            lg = dot_h2(a.z, b.z, lg); lg = dot_h2(a.w, b.w, lg);
        }
        lg *= 0.25f;   // 1/sqrt(ADIM=16)
        // logits bounded (|lg| << 88): f32 exp safe without max subtraction
        float e = __expf(lg);
        float sum = e;
#pragma unroll
        for (int off = 16; off; off >>= 1) sum += __shfl_xor(sum, off);
        attn_s[h * 36 + k] = e / sum;
    }
    __syncthreads();

    // single-pass epilogue: 2 output cols/thread, packed b32 LDS reads + v_fma_mix.
    // Branches align to wave boundaries.
    ushort* od = &ovec[(size_t)n * 512];
    if (t < 64) {               // o: cols 2t,2t+1 of msgv part
        const int hh = t >> 3;
        const float* ap = &attn_s[hh * 36];
        const ushort* src = &kvv[2 * t];
        float a0 = 0.f, a1 = 0.f;
#pragma unroll
        for (int i8 = 0; i8 < 8; ++i8) {
            float4 av = *(const float4*)&ap[i8 * 4];
            fma2(av.x, *(const uint*)&src[(i8 * 4 + 0) * 128], a0, a1);
            fma2(av.y, *(const uint*)&src[(i8 * 4 + 1) * 128], a0, a1);
            fma2(av.z, *(const uint*)&src[(i8 * 4 + 2) * 128], a0, a1);
            fma2(av.w, *(const uint*)&src[(i8 * 4 + 3) * 128], a0, a1);
        }
        *(uint*)&od[2 * t] = pack2h(a0, a1);
    } else if (t < 192) {       // wd: head hh, dist dims d0,d0+1
        const int i = t - 64;
        const int hh = i >> 4, d0 = (i & 15) * 2;
        const float* ap = &attn_s[hh * 36];
        const ushort* src = &distsH[d0];
        float a0 = 0.f, a1 = 0.f;
#pragma unroll
        for (int i8 = 0; i8 < 8; ++i8) {
            float4 av = *(const float4*)&ap[i8 * 4];
            fma2(av.x, *(const uint*)&src[(i8 * 4 + 0) * LDDH], a0, a1);
            fma2(av.y, *(const uint*)&src[(i8 * 4 + 1) * LDDH], a0, a1);
            fma2(av.z, *(const uint*)&src[(i8 * 4 + 2) * LDDH], a0, a1);
            fma2(av.w, *(const uint*)&src[(i8 * 4 + 3) * LDDH], a0, a1);
        }
        *(uint*)&od[128 + hh * 32 + d0] = pack2h(a0, a1);
    } else {                    // ws: head hh, seq dims s0,s0+1
        const int i = t - 192;
        const int hh = i >> 3, s0 = (i & 7) * 2;
        const float* ap = &attn_s[hh * 36];
        const ushort* src = &seqsH[s0];
        float a0 = 0.f, a1 = 0.f;
#pragma unroll
        for (int i8 = 0; i8 < 8; ++i8) {
            float4 av = *(const float4*)&ap[i8 * 4];
            fma2(av.x, *(const uint*)&src[(i8 * 4 + 0) * LDSH], a0, a1);
            fma2(av.y, *(const uint*)&src[(i8 * 4 + 1) * LDSH], a0, a1);
            fma2(av.z, *(const uint*)&src[(i8 * 4 + 2) * LDSH], a0, a1);
            fma2(av.w, *(const uint*)&src[(i8 * 4 + 3) * LDSH], a0, a1);
        }
        *(uint*)&od[384 + hh * 16 + s0] = pack2h(a0, a1);
    }
}

// ================= final: out = features + ovec(f16) @ BigW + cvec =================
__global__ __launch_bounds__(256) void final_kernel(
    const ushort* __restrict__ ovec, const float* __restrict__ BigW,
    const float* __restrict__ cvec, const float* __restrict__ features,
    float* __restrict__ out)
{
    __shared__ __align__(16) float bufA[TM * LDA];
    const int t = threadIdx.x;
    const int node0 = blockIdx.x * TM;
    const int m0 = (t >> 5) * 4;
    const int c0 = (t & 31) * 4;
    float acc[4][4];
#pragma unroll
    for (int mm = 0; mm < 4; ++mm)
#pragma unroll
        for (int cc = 0; cc < 4; ++cc) acc[mm][cc] = 0.f;

    for (int ck = 0; ck < 4; ++ck) {
        __syncthreads();
#pragma unroll
        for (int r = 0; r < 4; ++r) {
            int fid = t + 256 * r;
            int row = fid >> 5, c4 = (fid & 31) * 4;
            uint2 u = *(const uint2*)&ovec[(size_t)(node0 + row) * 512 + ck * 128 + c4];
            float2 a = h2f2(u.x), b = h2f2(u.y);
            *(float4*)&bufA[row * LDA + c4] = make_float4(a.x, a.y, b.x, b.y);
        }
        __syncthreads();
        const float* Wc = BigW + ck * 128 * 128;
#pragma unroll 4
        for (int ic = 0; ic < 32; ++ic) {
            float a[4][4];
#pragma unroll
            for (int mm = 0; mm < 4; ++mm) {
                float4 av = *(const float4*)&bufA[(m0 + mm) * LDA + ic * 4];
                a[mm][0] = av.x; a[mm][1] = av.y; a[mm][2] = av.z; a[mm][3] = av.w;
            }
            float w[4][4];
#pragma unroll
            for (int ii = 0; ii < 4; ++ii) {
                float4 wv = *(const float4*)&Wc[(ic * 4 + ii) * 128 + c0];
                w[ii][0] = wv.x; w[ii][1] = wv.y; w[ii][2] = wv.z; w[ii][3] = wv.w;
            }
#pragma unroll
            for (int mm = 0; mm < 4; ++mm)
#pragma unroll
                for (int ii = 0; ii < 4; ++ii) {
                    float av = a[mm][ii];
#pragma unroll
                    for (int cc = 0; cc < 4; ++cc)
                        acc[mm][cc] = fmaf(av, w[ii][cc], acc[mm][cc]);
                }
        }
    }
    float4 cv = *(const float4*)&cvec[c0];
#pragma unroll
    for (int mm = 0; mm < 4; ++mm) {
        float4 f = *(const float4*)&features[(size_t)(node0 + m0 + mm) * 128 + c0];
        *(float4*)&out[(size_t)(node0 + m0 + mm) * 128 + c0] =
            make_float4(acc[mm][0] + f.x + cv.x, acc[mm][1] + f.y + cv.y,
                        acc[mm][2] + f.z + cv.z, acc[mm][3] + f.w + cv.w);
    }
}

extern "C" void kernel_launch(void* const* d_in, const int* in_sizes, int n_in,
                              void* d_out, int out_size, void* d_ws, size_t ws_size,
                              hipStream_t stream)
{
    const float* features = (const float*)d_in[0];
    const float* dist     = (const float*)d_in[1];
    const float* seq      = (const float*)d_in[2];
    const float* enc      = (const float*)d_in[3];
    const int*   idx      = (const int*)d_in[4];
    const float* W1 = (const float*)d_in[5];
    const float* b1 = (const float*)d_in[6];
    const float* W2 = (const float*)d_in[7];
    const float* b2 = (const float*)d_in[8];
    const float* W3 = (const float*)d_in[9];
    const float* b3 = (const float*)d_in[10];
    const float* Wq = (const float*)d_in[11];
    const float* bq = (const float*)d_in[12];
    const float* Wk = (const float*)d_in[13];
    // d_in[14] = bk: dropped (softmax-invariant)
    const float* Wv = (const float*)d_in[15];
    const float* bv = (const float*)d_in[16];
    const float* Wo = (const float*)d_in[17];
    const float* bo = (const float*)d_in[18];
    float* out = (float*)d_out;

    // Workspace: kv 8 | qext 16 | ovec 16 | BigW 256K | cvec | wpack 192K  (~40.5 MB)
    char* ws = (char*)d_ws;
    ushort* kv    = (ushort*)ws;
    ushort* qext  = (ushort*)(ws + ((size_t)8  << 20));
    ushort* ovec  = (ushort*)(ws + ((size_t)24 << 20));
    float*  BigW  = (float*)(ws + ((size_t)40 << 20));
    float*  cvec  = (float*)(ws + ((size_t)40 << 20) + 262144);
    ushort* wpack = (ushort*)(ws + ((size_t)40 << 20) + 262144 + 512);

    prep_kernel<<<704, 128, 0, stream>>>(Wv, Wo, bv, bo, W1, W2, W3, Wq, Wk,
                                         BigW, cvec, wpack);
    phaseA_kernel<<<NN / TM, 256, 0, stream>>>(
        features, enc, b1, b2, b3, bq, Wk, wpack, qext, kv);
    attn_kernel<<<NN, 256, 0, stream>>>(qext, kv, dist, seq, idx, ovec);
    final_kernel<<<NN / TM, 256, 0, stream>>>(ovec, BigW, cvec, features, out);
}

// Round 13
// 225.111 us; speedup vs baseline: 1.2099x; 1.1332x over previous
//
#include <hip/hip_runtime.h>
#include <hip/hip_fp16.h>
#include <math.h>

#define NN 16384
#define TM 32
#define LDH 136   // f16 LDS row stride (128 + 8 pad, keeps 16B alignment)
#define LDO 520   // ovec f16 LDS stride (512 + 8, 16B-aligned, 2-way-free banks)
#define LDDH 40   // dists f16 stride (80 B rows, 16B-aligned)
#define LDSH 24   // seqs f16 stride (48 B rows, 16B-aligned)

typedef unsigned int uint;
typedef unsigned short ushort;
typedef _Float16 half8 __attribute__((ext_vector_type(8)));
typedef _Float16 half2v __attribute__((ext_vector_type(2)));
typedef float floatx4 __attribute__((ext_vector_type(4)));

__device__ __forceinline__ uint pack2h(float a, float b) {
    _Float16 ha = (_Float16)a, hb = (_Float16)b;
    ushort ua = *(ushort*)&ha, ub = *(ushort*)&hb;
    return (uint)ua | ((uint)ub << 16);
}
__device__ __forceinline__ float2 h2f2(uint u) {
    __half2 h = *(__half2*)&u;
    return __half22float2(h);
}
// packed f16 pair dot with f32 accumulate — single v_dot2_f32_f16
__device__ __forceinline__ float dot_h2(uint a, uint b, float acc) {
    half2v ha = *(half2v*)&a, hb = *(half2v*)&b;
    return __builtin_amdgcn_fdot2(ha, hb, acc, false);
}
// f32 scalar × packed-f16 pair -> two f32 accumulators (2× v_fma_mix_f32)
__device__ __forceinline__ void fma2(float a, uint v, float& acc0, float& acc1) {
    __half2 h = *(__half2*)&v;
    acc0 += a * (float)__low2half(h);
    acc1 += a * (float)__high2half(h);
}

// ================= phaseA: MFMA f16 fused 6-GEMM chain + qext =================
// A-frag: A[m=lane&15][k=quad*8+j]  B-frag: B[k=quad*8+j][n=lane&15]
// C/D: col=lane&15, row=quad*4+reg (m89-verified).

struct Acc4 { floatx4 a[4]; };

template<bool RELUA>
__device__ __forceinline__ Acc4 mfma_gemm(const ushort* Ab, const half8* wp, int lane, int w)
{
    const int m  = (w & 1) * 16 + (lane & 15);
    const int kq = (lane >> 4) * 8;
    const int cg = w >> 1;
    half8 afr[4];
#pragma unroll
    for (int ks = 0; ks < 4; ++ks) {
        afr[ks] = *(const half8*)&Ab[m * LDH + ks * 32 + kq];
        if (RELUA) {
#pragma unroll
            for (int j = 0; j < 8; ++j)
                afr[ks][j] = afr[ks][j] > (_Float16)0.f ? afr[ks][j] : (_Float16)0.f;
        }
    }
    Acc4 r;
#pragma unroll
    for (int ct = 0; ct < 4; ++ct) {
        const int CT = cg * 4 + ct;
        floatx4 acc = {0.f, 0.f, 0.f, 0.f};
#pragma unroll
        for (int ks = 0; ks < 4; ++ks) {
            half8 bfr = wp[(CT * 4 + ks) * 64 + lane];
            acc = __builtin_amdgcn_mfma_f32_16x16x32_f16(afr[ks], bfr, acc, 0, 0, 0);
        }
        r.a[ct] = acc;
    }
    return r;
}

template<bool HAS_BIAS, bool RELU, bool HAS_ENC>
__device__ __forceinline__ void epilogue(const Acc4& ac, const float* __restrict__ bias,
    const float* __restrict__ enc, ushort* dst16, int node0, int lane, int w)
{
    const int row0 = (w & 1) * 16 + ((lane >> 4) << 2);
    const int cg = w >> 1;
#pragma unroll
    for (int ct = 0; ct < 4; ++ct) {
        const int col = (cg * 4 + ct) * 16 + (lane & 15);
        float bb = HAS_BIAS ? bias[col] : 0.f;
#pragma unroll
        for (int r = 0; r < 4; ++r) {
            float x = ac.a[ct][r] + bb;
            if (RELU) x = fmaxf(x, 0.f);
            if (HAS_ENC) x += enc[(size_t)(node0 + row0 + r) * 128 + col];
            _Float16 h = (_Float16)x;
            dst16[(row0 + r) * LDH + col] = *(ushort*)&h;
        }
    }
}

// LDS 38,400 B -> 4 blocks/CU. qstage/wk in f16.
__global__ __launch_bounds__(256, 4) void phaseA_kernel(
    const float* __restrict__ features, const float* __restrict__ enc,
    const float* __restrict__ b1, const float* __restrict__ b2,
    const float* __restrict__ b3, const float* __restrict__ bq,
    const float* __restrict__ Wk, const ushort* __restrict__ wpack,
    ushort* __restrict__ qext, ushort* __restrict__ kv)
{
    __shared__ __align__(16) ushort bufA[TM * LDH];
    __shared__ __align__(16) ushort bufB[TM * LDH];
    __shared__ __align__(16) ushort qstageH[TM * LDH];  // q f16; later V stage
    __shared__ __align__(16) ushort wkH[48 * 128];      // Wk_ext f16

    const int t = threadIdx.x;
    const int lane = t & 63, w = t >> 6;
    const int node0 = blockIdx.x * TM;

    const half8* wpQ = (const half8*)(wpack + 0 * 16384);
    const half8* wp1 = (const half8*)(wpack + 1 * 16384);
    const half8* wp2 = (const half8*)(wpack + 2 * 16384);
    const half8* wp3 = (const half8*)(wpack + 3 * 16384);
    const half8* wpK = (const half8*)(wpack + 4 * 16384);
    const half8* wpV = (const half8*)(wpack + 5 * 16384);

#pragma unroll
    for (int r = 0; r < 4; ++r) {
        int fid = t + 256 * r;
        int row = fid >> 5, c4 = (fid & 31) * 4;
        float4 v = *(const float4*)&features[(size_t)(node0 + row) * 128 + c4];
        uint2 h = make_uint2(pack2h(v.x, v.y), pack2h(v.z, v.w));
        *(uint2*)&bufA[row * LDH + c4] = h;
    }
#pragma unroll
    for (int r = 0; r < 6; ++r) {
        int fid = t + 256 * r;
        float4 v = *(const float4*)&Wk[128 * 128 + fid * 4];
        *(uint2*)&wkH[fid * 4] = make_uint2(pack2h(v.x, v.y), pack2h(v.z, v.w));
    }
    __syncthreads();

    Acc4 aQ = mfma_gemm<false>(bufA, wpQ, lane, w);          // q = F@Wq
    Acc4 a1 = mfma_gemm<true >(bufA, wp1, lane, w);          // relu(F)@W1
    epilogue<true, false, false>(aQ, bq, nullptr, qstageH, node0, lane, w);
    epilogue<true, true,  false>(a1, b1, nullptr, bufB,    node0, lane, w);
    __syncthreads();

    Acc4 a2 = mfma_gemm<false>(bufB, wp2, lane, w);          // h1@W2

    // fused qext: per (node m, head hh): 48 ext dots via fdot2 + q copy, f16
    {
        const int m = t >> 3, hh = t & 7;
        uint qu[8];
        *(uint4*)&qu[0] = *(const uint4*)&qstageH[m * LDH + hh * 16];
        *(uint4*)&qu[4] = *(const uint4*)&qstageH[m * LDH + hh * 16 + 8];
        ushort* dst = &qext[(size_t)(node0 + m) * 512 + hh * 64];
#pragma unroll
        for (int x0 = 0; x0 < 48; x0 += 8) {
            float res[8];
#pragma unroll
            for (int xx = 0; xx < 8; ++xx) {
                const ushort* wr = &wkH[(x0 + xx) * 128 + hh * 16];
                uint4 w0 = *(const uint4*)&wr[0];
                uint4 w1 = *(const uint4*)&wr[8];
                float s = 0.f;
                s = dot_h2(qu[0], w0.x, s); s = dot_h2(qu[1], w0.y, s);
                s = dot_h2(qu[2], w0.z, s); s = dot_h2(qu[3], w0.w, s);
                s = dot_h2(qu[4], w1.x, s); s = dot_h2(qu[5], w1.y, s);
                s = dot_h2(qu[6], w1.z, s); s = dot_h2(qu[7], w1.w, s);
                res[xx] = s;
            }
            *(uint4*)&dst[x0] = make_uint4(pack2h(res[0], res[1]), pack2h(res[2], res[3]),
                                           pack2h(res[4], res[5]), pack2h(res[6], res[7]));
        }
        *(uint4*)&dst[48] = *(const uint4*)&qu[0];
        *(uint4*)&dst[56] = *(const uint4*)&qu[4];
    }
    epilogue<true, true, false>(a2, b2, nullptr, bufA, node0, lane, w);
    __syncthreads();

    Acc4 a3 = mfma_gemm<false>(bufA, wp3, lane, w);          // h2@W3
    epilogue<true, true, true>(a3, b3, enc, bufB, node0, lane, w);  // msg
    __syncthreads();

    Acc4 aK = mfma_gemm<false>(bufB, wpK, lane, w);          // msg@Wk[:128]
    Acc4 aV = mfma_gemm<false>(bufB, wpV, lane, w);          // msg@Wv[:128]
    epilogue<false, false, false>(aK, nullptr, nullptr, bufA,    node0, lane, w);
    epilogue<false, false, false>(aV, nullptr, nullptr, qstageH, node0, lane, w);
    __syncthreads();

    {
        int row = t >> 3, c16 = (t & 7) * 16;
        size_t kbase = (size_t)(node0 + row) * 256;
        *(uint4*)&kv[kbase + c16]           = *(const uint4*)&bufA[row * LDH + c16];
        *(uint4*)&kv[kbase + c16 + 8]       = *(const uint4*)&bufA[row * LDH + c16 + 8];
        *(uint4*)&kv[kbase + 128 + c16]     = *(const uint4*)&qstageH[row * LDH + c16];
        *(uint4*)&kv[kbase + 128 + c16 + 8] = *(const uint4*)&qstageH[row * LDH + c16 + 8];
    }
}

// ===== prep: BigWp f16 MFMA-B-frag pack / cvec (0..511) + wpack (512..703) =====
__global__ void prep_kernel(
    const float* __restrict__ Wv, const float* __restrict__ Wo,
    const float* __restrict__ bv, const float* __restrict__ bo,
    const float* __restrict__ W1, const float* __restrict__ W2,
    const float* __restrict__ W3, const float* __restrict__ Wq,
    const float* __restrict__ Wk,
    ushort* __restrict__ BigWp, float* __restrict__ cvec,
    ushort* __restrict__ wpack)
{
    const int r = blockIdx.x;
    const int c = threadIdx.x;
    if (r < 512) {
        float s = 0.f;
        if (r < 128) {
            s = Wo[r * 128 + c];
        } else if (r < 384) {
            int x = r - 128; int hh = x >> 5, d = x & 31;
#pragma unroll
            for (int a = 0; a < 16; ++a)
                s += Wv[(128 + d) * 128 + hh * 16 + a] * Wo[(hh * 16 + a) * 128 + c];
        } else {
            int x = r - 384; int hh = x >> 4, ss = x & 15;
#pragma unroll
            for (int a = 0; a < 16; ++a)
                s += Wv[(160 + ss) * 128 + hh * 16 + a] * Wo[(hh * 16 + a) * 128 + c];
        }
        // scatter into MFMA B-frag layout: k=r, n=c
        {
            const int CT = c >> 4, nin = c & 15;
            const int ks = r >> 5, rem = r & 31, quad = rem >> 3, j = rem & 7;
            const int lane = quad * 16 + nin;
            _Float16 hs = (_Float16)s;
            BigWp[(size_t)(((CT * 16 + ks) * 64 + lane) * 8 + j)] = *(ushort*)&hs;
        }
        if (r == 0) {
            float cv = bo[c];
            for (int jj = 0; jj < 128; ++jj) cv += bv[jj] * Wo[jj * 128 + c];
            cvec[c] = cv;
        }
    } else {
        if (c >= 64) return;
        const int bb = r - 512;          // 0..191
        const int g = bb >> 5;
        const int rem = bb & 31;
        const int CT = rem >> 2, ks = rem & 3;
        const float* W = (g == 0) ? Wq : (g == 1) ? W1 : (g == 2) ? W2
                       : (g == 3) ? W3 : (g == 4) ? Wk : Wv;
        const int n = CT * 16 + (c & 15);
        const int k0 = ks * 32 + (c >> 4) * 8;
        ushort out[8];
#pragma unroll
        for (int j = 0; j < 8; ++j) {
            _Float16 h = (_Float16)W[(k0 + j) * 128 + n];
            out[j] = *(ushort*)&h;
        }
        *(uint4*)&wpack[(size_t)(((g * 8 + CT) * 4 + ks) * 64 + c) * 8] = *(uint4*)out;
    }
}

// ==== attn: R10 (qeH LDS, fdot2, max-free softmax, full occupancy) — unchanged ====
__global__ __launch_bounds__(256, 8) void attn_kernel(
    const ushort* __restrict__ qext, const ushort* __restrict__ kv,
    const float* __restrict__ dist, const float* __restrict__ seq,
    const int* __restrict__ idx, ushort* __restrict__ ovec)
{
    __shared__ __align__(16) ushort distsH[32 * LDDH];
    __shared__ __align__(16) ushort seqsH[32 * LDSH];
    __shared__ __align__(16) ushort qeH[512];       // [h*64 + {48 ext | 16 q}]
    __shared__ __align__(16) float attn_s[8 * 36];  // stride 36 -> conflict-free bcast
    __shared__ __align__(16) ushort kvv[32 * 128];

    const int t = threadIdx.x;
    const int n = blockIdx.x;
    const int h = t >> 5, k = t & 31;

    int j = idx[n * 32 + k];
    const uint4* mkp = (const uint4*)(kv + (size_t)j * 256 + h * 16);
    uint4 mk0 = mkp[0], mk1 = mkp[1];

    {   // msgv half -> LDS rows (8 threads/row)
        int r = t >> 3, cc = t & 7;
        int j2 = idx[n * 32 + r];
        const uint4* vp = (const uint4*)(kv + (size_t)j2 * 256 + 128 + cc * 16);
        uint4 v0 = vp[0], v1 = vp[1];
        *(uint4*)&kvv[r * 128 + cc * 16] = v0;
        *(uint4*)&kvv[r * 128 + cc * 16 + 8] = v1;
    }
    {   // dists -> f16, stride 40 halves
        float4 v = *(const float4*)&dist[(size_t)n * 1024 + t * 4];
        int kk = t >> 3, d0 = (t & 7) * 4;
        *(uint2*)&distsH[kk * LDDH + d0] = make_uint2(pack2h(v.x, v.y), pack2h(v.z, v.w));
    }
    if (t < 128) {   // seqs -> f16, stride 24 halves
        float4 v = *(const float4*)&seq[(size_t)n * 512 + t * 4];
        int kk = t >> 2, s0 = (t & 3) * 4;
        *(uint2*)&seqsH[kk * LDSH + s0] = make_uint2(pack2h(v.x, v.y), pack2h(v.z, v.w));
    }
    if (t < 64)      // qext stays f16 — raw copy, no unpack
        *(uint4*)&qeH[t * 8] = *(const uint4*)&qext[(size_t)n * 512 + t * 8];
    __syncthreads();

    {   // logits: 64 v_dot2_f32_f16 + 14 b128 LDS reads; max-free softmax
        float lg = 0.f;
        const uint4* qhp = (const uint4*)&qeH[h * 64 + 48];
        uint4 q0 = qhp[0], q1 = qhp[1];
        lg = dot_h2(mk0.x, q0.x, lg); lg = dot_h2(mk0.y, q0.y, lg);
        lg = dot_h2(mk0.z, q0.z, lg); lg = dot_h2(mk0.w, q0.w, lg);
        lg = dot_h2(mk1.x, q1.x, lg); lg = dot_h2(mk1.y, q1.y, lg);
        lg = dot_h2(mk1.z, q1.z, lg); lg = dot_h2(mk1.w, q1.w, lg);
        const uint4* drp = (const uint4*)&distsH[k * LDDH];
        const uint4* qdp = (const uint4*)&qeH[h * 64];
#pragma unroll
        for (int i = 0; i < 4; ++i) {
            uint4 a = drp[i], b = qdp[i];
            lg = dot_h2(a.x, b.x, lg); lg = dot_h2(a.y, b.y, lg);
            lg = dot_h2(a.z, b.z, lg); lg = dot_h2(a.w, b.w, lg);
        }
        const uint4* srp = (const uint4*)&seqsH[k * LDSH];
        const uint4* qsp = (const uint4*)&qeH[h * 64 + 32];
#pragma unroll
        for (int i = 0; i < 2; ++i) {
            uint4 a = srp[i], b = qsp[i];
            lg = dot_h2(a.x, b.x, lg); lg = dot_h2(a.y, b.y, lg);
            lg = dot_h2(a.z, b.z, lg); lg = dot_h2(a.w, b.w, lg);
        }
        lg *= 0.25f;   // 1/sqrt(ADIM=16)
        // logits bounded (|lg| << 88): f32 exp safe without max subtraction
        float e = __expf(lg);
        float sum = e;
#pragma unroll
        for (int off = 16; off; off >>= 1) sum += __shfl_xor(sum, off);
        attn_s[h * 36 + k] = e / sum;
    }
    __syncthreads();

    // single-pass epilogue: 2 output cols/thread, packed b32 LDS reads + v_fma_mix.
    // Branches align to wave boundaries.
    ushort* od = &ovec[(size_t)n * 512];
    if (t < 64) {               // o: cols 2t,2t+1 of msgv part
        const int hh = t >> 3;
        const float* ap = &attn_s[hh * 36];
        const ushort* src = &kvv[2 * t];
        float a0 = 0.f, a1 = 0.f;
#pragma unroll
        for (int i8 = 0; i8 < 8; ++i8) {
            float4 av = *(const float4*)&ap[i8 * 4];
            fma2(av.x, *(const uint*)&src[(i8 * 4 + 0) * 128], a0, a1);
            fma2(av.y, *(const uint*)&src[(i8 * 4 + 1) * 128], a0, a1);
            fma2(av.z, *(const uint*)&src[(i8 * 4 + 2) * 128], a0, a1);
            fma2(av.w, *(const uint*)&src[(i8 * 4 + 3) * 128], a0, a1);
        }
        *(uint*)&od[2 * t] = pack2h(a0, a1);
    } else if (t < 192) {       // wd: head hh, dist dims d0,d0+1
        const int i = t - 64;
        const int hh = i >> 4, d0 = (i & 15) * 2;
        const float* ap = &attn_s[hh * 36];
        const ushort* src = &distsH[d0];
        float a0 = 0.f, a1 = 0.f;
#pragma unroll
        for (int i8 = 0; i8 < 8; ++i8) {
            float4 av = *(const float4*)&ap[i8 * 4];
            fma2(av.x, *(const uint*)&src[(i8 * 4 + 0) * LDDH], a0, a1);
            fma2(av.y, *(const uint*)&src[(i8 * 4 + 1) * LDDH], a0, a1);
            fma2(av.z, *(const uint*)&src[(i8 * 4 + 2) * LDDH], a0, a1);
            fma2(av.w, *(const uint*)&src[(i8 * 4 + 3) * LDDH], a0, a1);
        }
        *(uint*)&od[128 + hh * 32 + d0] = pack2h(a0, a1);
    } else {                    // ws: head hh, seq dims s0,s0+1
        const int i = t - 192;
        const int hh = i >> 3, s0 = (i & 7) * 2;
        const float* ap = &attn_s[hh * 36];
        const ushort* src = &seqsH[s0];
        float a0 = 0.f, a1 = 0.f;
#pragma unroll
        for (int i8 = 0; i8 < 8; ++i8) {
            float4 av = *(const float4*)&ap[i8 * 4];
            fma2(av.x, *(const uint*)&src[(i8 * 4 + 0) * LDSH], a0, a1);
            fma2(av.y, *(const uint*)&src[(i8 * 4 + 1) * LDSH], a0, a1);
            fma2(av.z, *(const uint*)&src[(i8 * 4 + 2) * LDSH], a0, a1);
            fma2(av.w, *(const uint*)&src[(i8 * 4 + 3) * LDSH], a0, a1);
        }
        *(uint*)&od[384 + hh * 16 + s0] = pack2h(a0, a1);
    }
}

// ======= final (MFMA): out = features + ovec(f16)[K=512] @ BigWp(f16) + cvec =======
__global__ __launch_bounds__(256, 4) void final_kernel(
    const ushort* __restrict__ ovec, const ushort* __restrict__ BigWp,
    const float* __restrict__ cvec, const float* __restrict__ features,
    float* __restrict__ out)
{
    __shared__ __align__(16) ushort bufO[TM * LDO];  // 32 rows x 512 halves
    const int t = threadIdx.x;
    const int lane = t & 63, w = t >> 6;
    const int node0 = blockIdx.x * TM;

#pragma unroll
    for (int i = 0; i < 16; ++i) {
        int fid = t + 256 * i;          // uint4 index, 0..4095
        int row = fid >> 6, c8 = (fid & 63) * 8;
        *(uint4*)&bufO[row * LDO + c8] = *(const uint4*)&ovec[(size_t)(node0 + row) * 512 + c8];
    }
    __syncthreads();

    const int m  = (w & 1) * 16 + (lane & 15);
    const int kq = (lane >> 4) * 8;
    const int cg = w >> 1;
    const half8* bp = (const half8*)BigWp;

    floatx4 acc[4];
#pragma unroll
    for (int ct = 0; ct < 4; ++ct) acc[ct] = (floatx4){0.f, 0.f, 0.f, 0.f};

#pragma unroll
    for (int ks = 0; ks < 16; ++ks) {
        half8 afr = *(const half8*)&bufO[m * LDO + ks * 32 + kq];
#pragma unroll
        for (int ct = 0; ct < 4; ++ct) {
            const int CT = cg * 4 + ct;
            half8 bfr = bp[(CT * 16 + ks) * 64 + lane];
            acc[ct] = __builtin_amdgcn_mfma_f32_16x16x32_f16(afr, bfr, acc[ct], 0, 0, 0);
        }
    }

    // C/D: col=lane&15, row=quad*4+reg
    const int row0 = (w & 1) * 16 + ((lane >> 4) << 2);
#pragma unroll
    for (int ct = 0; ct < 4; ++ct) {
        const int col = (cg * 4 + ct) * 16 + (lane & 15);
        float cv = cvec[col];
#pragma unroll
        for (int r = 0; r < 4; ++r) {
            const size_t grow = (size_t)(node0 + row0 + r);
            out[grow * 128 + col] = acc[ct][r] + features[grow * 128 + col] + cv;
        }
    }
}

extern "C" void kernel_launch(void* const* d_in, const int* in_sizes, int n_in,
                              void* d_out, int out_size, void* d_ws, size_t ws_size,
                              hipStream_t stream)
{
    const float* features = (const float*)d_in[0];
    const float* dist     = (const float*)d_in[1];
    const float* seq      = (const float*)d_in[2];
    const float* enc      = (const float*)d_in[3];
    const int*   idx      = (const int*)d_in[4];
    const float* W1 = (const float*)d_in[5];
    const float* b1 = (const float*)d_in[6];
    const float* W2 = (const float*)d_in[7];
    const float* b2 = (const float*)d_in[8];
    const float* W3 = (const float*)d_in[9];
    const float* b3 = (const float*)d_in[10];
    const float* Wq = (const float*)d_in[11];
    const float* bq = (const float*)d_in[12];
    const float* Wk = (const float*)d_in[13];
    // d_in[14] = bk: dropped (softmax-invariant)
    const float* Wv = (const float*)d_in[15];
    const float* bv = (const float*)d_in[16];
    const float* Wo = (const float*)d_in[17];
    const float* bo = (const float*)d_in[18];
    float* out = (float*)d_out;

    // Workspace: kv 8M | qext 16M | ovec 16M | BigWp 128K | cvec 512B | wpack 192K
    char* ws = (char*)d_ws;
    ushort* kv    = (ushort*)ws;
    ushort* qext  = (ushort*)(ws + ((size_t)8  << 20));
    ushort* ovec  = (ushort*)(ws + ((size_t)24 << 20));
    ushort* BigWp = (ushort*)(ws + ((size_t)40 << 20));
    float*  cvec  = (float*)(ws + ((size_t)40 << 20) + 131072);
    ushort* wpack = (ushort*)(ws + ((size_t)40 << 20) + 131072 + 512);

    prep_kernel<<<704, 128, 0, stream>>>(Wv, Wo, bv, bo, W1, W2, W3, Wq, Wk,
                                         BigWp, cvec, wpack);
    phaseA_kernel<<<NN / TM, 256, 0, stream>>>(
        features, enc, b1, b2, b3, bq, Wk, wpack, qext, kv);
    attn_kernel<<<NN, 256, 0, stream>>>(qext, kv, dist, seq, idx, ovec);
    final_kernel<<<NN / TM, 256, 0, stream>>>(ovec, BigWp, cvec, features, out);
}

// Round 14
// 223.133 us; speedup vs baseline: 1.2206x; 1.0089x over previous
//
#include <hip/hip_runtime.h>
#include <hip/hip_fp16.h>
#include <math.h>

#define NN 16384
#define TM 32
#define LDH 136   // f16 LDS row stride (128 + 8 pad, keeps 16B alignment)
#define LDO 520   // ovec f16 LDS stride (512 + 8, 16B-aligned, 2-way-free banks)
#define LDDH 40   // dists f16 stride (80 B rows, 16B-aligned)
#define LDSH 24   // seqs f16 stride (48 B rows, 16B-aligned)

typedef unsigned int uint;
typedef unsigned short ushort;
typedef _Float16 half8 __attribute__((ext_vector_type(8)));
typedef _Float16 half2v __attribute__((ext_vector_type(2)));
typedef float floatx4 __attribute__((ext_vector_type(4)));

__device__ __forceinline__ uint pack2h(float a, float b) {
    _Float16 ha = (_Float16)a, hb = (_Float16)b;
    ushort ua = *(ushort*)&ha, ub = *(ushort*)&hb;
    return (uint)ua | ((uint)ub << 16);
}
__device__ __forceinline__ float2 h2f2(uint u) {
    __half2 h = *(__half2*)&u;
    return __half22float2(h);
}
// packed f16 pair dot with f32 accumulate — single v_dot2_f32_f16
__device__ __forceinline__ float dot_h2(uint a, uint b, float acc) {
    half2v ha = *(half2v*)&a, hb = *(half2v*)&b;
    return __builtin_amdgcn_fdot2(ha, hb, acc, false);
}
// f32 scalar × packed-f16 pair -> two f32 accumulators (2× v_fma_mix_f32)
__device__ __forceinline__ void fma2(float a, uint v, float& acc0, float& acc1) {
    __half2 h = *(__half2*)&v;
    acc0 += a * (float)__low2half(h);
    acc1 += a * (float)__high2half(h);
}

// ================= phaseA: MFMA f16 fused 6-GEMM chain + qext =================
// A-frag: A[m=lane&15][k=quad*8+j]  B-frag: B[k=quad*8+j][n=lane&15]
// C/D: col=lane&15, row=quad*4+reg (m89-verified).

struct Acc4 { floatx4 a[4]; };

template<bool RELUA>
__device__ __forceinline__ Acc4 mfma_gemm(const ushort* Ab, const half8* wp, int lane, int w)
{
    const int m  = (w & 1) * 16 + (lane & 15);
    const int kq = (lane >> 4) * 8;
    const int cg = w >> 1;
    half8 afr[4];
#pragma unroll
    for (int ks = 0; ks < 4; ++ks) {
        afr[ks] = *(const half8*)&Ab[m * LDH + ks * 32 + kq];
        if (RELUA) {
#pragma unroll
            for (int j = 0; j < 8; ++j)
                afr[ks][j] = afr[ks][j] > (_Float16)0.f ? afr[ks][j] : (_Float16)0.f;
        }
    }
    Acc4 r;
#pragma unroll
    for (int ct = 0; ct < 4; ++ct) {
        const int CT = cg * 4 + ct;
        floatx4 acc = {0.f, 0.f, 0.f, 0.f};
#pragma unroll
        for (int ks = 0; ks < 4; ++ks) {
            half8 bfr = wp[(CT * 4 + ks) * 64 + lane];
            acc = __builtin_amdgcn_mfma_f32_16x16x32_f16(afr[ks], bfr, acc, 0, 0, 0);
        }
        r.a[ct] = acc;
    }
    return r;
}

template<bool HAS_BIAS, bool RELU, bool HAS_ENC>
__device__ __forceinline__ void epilogue(const Acc4& ac, const float* __restrict__ bias,
    const float* __restrict__ enc, ushort* dst16, int node0, int lane, int w)
{
    const int row0 = (w & 1) * 16 + ((lane >> 4) << 2);
    const int cg = w >> 1;
#pragma unroll
    for (int ct = 0; ct < 4; ++ct) {
        const int col = (cg * 4 + ct) * 16 + (lane & 15);
        float bb = HAS_BIAS ? bias[col] : 0.f;
#pragma unroll
        for (int r = 0; r < 4; ++r) {
            float x = ac.a[ct][r] + bb;
            if (RELU) x = fmaxf(x, 0.f);
            if (HAS_ENC) x += enc[(size_t)(node0 + row0 + r) * 128 + col];
            _Float16 h = (_Float16)x;
            dst16[(row0 + r) * LDH + col] = *(ushort*)&h;
        }
    }
}

// LDS 38,400 B -> 4 blocks/CU. qstage/wk in f16.
__global__ __launch_bounds__(256, 4) void phaseA_kernel(
    const float* __restrict__ features, const float* __restrict__ enc,
    const float* __restrict__ b1, const float* __restrict__ b2,
    const float* __restrict__ b3, const float* __restrict__ bq,
    const float* __restrict__ Wk, const ushort* __restrict__ wpack,
    ushort* __restrict__ qext, ushort* __restrict__ kv)
{
    __shared__ __align__(16) ushort bufA[TM * LDH];
    __shared__ __align__(16) ushort bufB[TM * LDH];
    __shared__ __align__(16) ushort qstageH[TM * LDH];  // q f16; later V stage
    __shared__ __align__(16) ushort wkH[48 * 128];      // Wk_ext f16

    const int t = threadIdx.x;
    const int lane = t & 63, w = t >> 6;
    const int node0 = blockIdx.x * TM;

    const half8* wpQ = (const half8*)(wpack + 0 * 16384);
    const half8* wp1 = (const half8*)(wpack + 1 * 16384);
    const half8* wp2 = (const half8*)(wpack + 2 * 16384);
    const half8* wp3 = (const half8*)(wpack + 3 * 16384);
    const half8* wpK = (const half8*)(wpack + 4 * 16384);
    const half8* wpV = (const half8*)(wpack + 5 * 16384);

#pragma unroll
    for (int r = 0; r < 4; ++r) {
        int fid = t + 256 * r;
        int row = fid >> 5, c4 = (fid & 31) * 4;
        float4 v = *(const float4*)&features[(size_t)(node0 + row) * 128 + c4];
        uint2 h = make_uint2(pack2h(v.x, v.y), pack2h(v.z, v.w));
        *(uint2*)&bufA[row * LDH + c4] = h;
    }
#pragma unroll
    for (int r = 0; r < 6; ++r) {
        int fid = t + 256 * r;
        float4 v = *(const float4*)&Wk[128 * 128 + fid * 4];
        *(uint2*)&wkH[fid * 4] = make_uint2(pack2h(v.x, v.y), pack2h(v.z, v.w));
    }
    __syncthreads();

    Acc4 aQ = mfma_gemm<false>(bufA, wpQ, lane, w);          // q = F@Wq
    Acc4 a1 = mfma_gemm<true >(bufA, wp1, lane, w);          // relu(F)@W1
    epilogue<true, false, false>(aQ, bq, nullptr, qstageH, node0, lane, w);
    epilogue<true, true,  false>(a1, b1, nullptr, bufB,    node0, lane, w);
    __syncthreads();

    Acc4 a2 = mfma_gemm<false>(bufB, wp2, lane, w);          // h1@W2

    // fused qext: per (node m, head hh): 48 ext dots via fdot2 + q copy, f16
    {
        const int m = t >> 3, hh = t & 7;
        uint qu[8];
        *(uint4*)&qu[0] = *(const uint4*)&qstageH[m * LDH + hh * 16];
        *(uint4*)&qu[4] = *(const uint4*)&qstageH[m * LDH + hh * 16 + 8];
        ushort* dst = &qext[(size_t)(node0 + m) * 512 + hh * 64];
#pragma unroll
        for (int x0 = 0; x0 < 48; x0 += 8) {
            float res[8];
#pragma unroll
            for (int xx = 0; xx < 8; ++xx) {
                const ushort* wr = &wkH[(x0 + xx) * 128 + hh * 16];
                uint4 w0 = *(const uint4*)&wr[0];
                uint4 w1 = *(const uint4*)&wr[8];
                float s = 0.f;
                s = dot_h2(qu[0], w0.x, s); s = dot_h2(qu[1], w0.y, s);
                s = dot_h2(qu[2], w0.z, s); s = dot_h2(qu[3], w0.w, s);
                s = dot_h2(qu[4], w1.x, s); s = dot_h2(qu[5], w1.y, s);
                s = dot_h2(qu[6], w1.z, s); s = dot_h2(qu[7], w1.w, s);
                res[xx] = s;
            }
            *(uint4*)&dst[x0] = make_uint4(pack2h(res[0], res[1]), pack2h(res[2], res[3]),
                                           pack2h(res[4], res[5]), pack2h(res[6], res[7]));
        }
        *(uint4*)&dst[48] = *(const uint4*)&qu[0];
        *(uint4*)&dst[56] = *(const uint4*)&qu[4];
    }
    epilogue<true, true, false>(a2, b2, nullptr, bufA, node0, lane, w);
    __syncthreads();

    Acc4 a3 = mfma_gemm<false>(bufA, wp3, lane, w);          // h2@W3
    epilogue<true, true, true>(a3, b3, enc, bufB, node0, lane, w);  // msg
    __syncthreads();

    Acc4 aK = mfma_gemm<false>(bufB, wpK, lane, w);          // msg@Wk[:128]
    Acc4 aV = mfma_gemm<false>(bufB, wpV, lane, w);          // msg@Wv[:128]
    epilogue<false, false, false>(aK, nullptr, nullptr, bufA,    node0, lane, w);
    epilogue<false, false, false>(aV, nullptr, nullptr, qstageH, node0, lane, w);
    __syncthreads();

    {
        int row = t >> 3, c16 = (t & 7) * 16;
        size_t kbase = (size_t)(node0 + row) * 256;
        *(uint4*)&kv[kbase + c16]           = *(const uint4*)&bufA[row * LDH + c16];
        *(uint4*)&kv[kbase + c16 + 8]       = *(const uint4*)&bufA[row * LDH + c16 + 8];
        *(uint4*)&kv[kbase + 128 + c16]     = *(const uint4*)&qstageH[row * LDH + c16];
        *(uint4*)&kv[kbase + 128 + c16 + 8] = *(const uint4*)&qstageH[row * LDH + c16 + 8];
    }
}

// ===== prep: BigWp f16 MFMA-B-frag pack / cvec (0..511) + wpack (512..703) =====
__global__ void prep_kernel(
    const float* __restrict__ Wv, const float* __restrict__ Wo,
    const float* __restrict__ bv, const float* __restrict__ bo,
    const float* __restrict__ W1, const float* __restrict__ W2,
    const float* __restrict__ W3, const float* __restrict__ Wq,
    const float* __restrict__ Wk,
    ushort* __restrict__ BigWp, float* __restrict__ cvec,
    ushort* __restrict__ wpack)
{
    const int r = blockIdx.x;
    const int c = threadIdx.x;
    if (r < 512) {
        float s = 0.f;
        if (r < 128) {
            s = Wo[r * 128 + c];
        } else if (r < 384) {
            int x = r - 128; int hh = x >> 5, d = x & 31;
#pragma unroll
            for (int a = 0; a < 16; ++a)
                s += Wv[(128 + d) * 128 + hh * 16 + a] * Wo[(hh * 16 + a) * 128 + c];
        } else {
            int x = r - 384; int hh = x >> 4, ss = x & 15;
#pragma unroll
            for (int a = 0; a < 16; ++a)
                s += Wv[(160 + ss) * 128 + hh * 16 + a] * Wo[(hh * 16 + a) * 128 + c];
        }
        // scatter into MFMA B-frag layout: k=r, n=c
        {
            const int CT = c >> 4, nin = c & 15;
            const int ks = r >> 5, rem = r & 31, quad = rem >> 3, j = rem & 7;
            const int lane = quad * 16 + nin;
            _Float16 hs = (_Float16)s;
            BigWp[(size_t)(((CT * 16 + ks) * 64 + lane) * 8 + j)] = *(ushort*)&hs;
        }
        if (r == 0) {
            float cv = bo[c];
            for (int jj = 0; jj < 128; ++jj) cv += bv[jj] * Wo[jj * 128 + c];
            cvec[c] = cv;
        }
    } else {
        if (c >= 64) return;
        const int bb = r - 512;          // 0..191
        const int g = bb >> 5;
        const int rem = bb & 31;
        const int CT = rem >> 2, ks = rem & 3;
        const float* W = (g == 0) ? Wq : (g == 1) ? W1 : (g == 2) ? W2
                       : (g == 3) ? W3 : (g == 4) ? Wk : Wv;
        const int n = CT * 16 + (c & 15);
        const int k0 = ks * 32 + (c >> 4) * 8;
        ushort out[8];
#pragma unroll
        for (int j = 0; j < 8; ++j) {
            _Float16 h = (_Float16)W[(k0 + j) * 128 + n];
            out[j] = *(ushort*)&h;
        }
        *(uint4*)&wpack[(size_t)(((g * 8 + CT) * 4 + ks) * 64 + c) * 8] = *(uint4*)out;
    }
}

// ==== attn: kvv staging removed — o-region reads V direct from L2 (uniform idx) ====
__global__ __launch_bounds__(256, 8) void attn_kernel(
    const ushort* __restrict__ qext, const ushort* __restrict__ kv,
    const float* __restrict__ dist, const float* __restrict__ seq,
    const int* __restrict__ idx, ushort* __restrict__ ovec)
{
    __shared__ __align__(16) ushort distsH[32 * LDDH];
    __shared__ __align__(16) ushort seqsH[32 * LDSH];
    __shared__ __align__(16) ushort qeH[512];       // [h*64 + {48 ext | 16 q}]
    __shared__ __align__(16) float attn_s[8 * 36];  // stride 36 -> conflict-free bcast

    const int t = threadIdx.x;
    const int n = blockIdx.x;
    const int h = t >> 5, k = t & 31;

    int j = idx[n * 32 + k];
    const uint4* mkp = (const uint4*)(kv + (size_t)j * 256 + h * 16);
    uint4 mk0 = mkp[0], mk1 = mkp[1];

    {   // dists -> f16, stride 40 halves
        float4 v = *(const float4*)&dist[(size_t)n * 1024 + t * 4];
        int kk = t >> 3, d0 = (t & 7) * 4;
        *(uint2*)&distsH[kk * LDDH + d0] = make_uint2(pack2h(v.x, v.y), pack2h(v.z, v.w));
    }
    if (t < 128) {   // seqs -> f16, stride 24 halves
        float4 v = *(const float4*)&seq[(size_t)n * 512 + t * 4];
        int kk = t >> 2, s0 = (t & 3) * 4;
        *(uint2*)&seqsH[kk * LDSH + s0] = make_uint2(pack2h(v.x, v.y), pack2h(v.z, v.w));
    }
    if (t < 64)      // qext stays f16 — raw copy, no unpack
        *(uint4*)&qeH[t * 8] = *(const uint4*)&qext[(size_t)n * 512 + t * 8];
    __syncthreads();

    {   // logits: 64 v_dot2_f32_f16 + 14 b128 LDS reads; max-free softmax
        float lg = 0.f;
        const uint4* qhp = (const uint4*)&qeH[h * 64 + 48];
        uint4 q0 = qhp[0], q1 = qhp[1];
        lg = dot_h2(mk0.x, q0.x, lg); lg = dot_h2(mk0.y, q0.y, lg);
        lg = dot_h2(mk0.z, q0.z, lg); lg = dot_h2(mk0.w, q0.w, lg);
        lg = dot_h2(mk1.x, q1.x, lg); lg = dot_h2(mk1.y, q1.y, lg);
        lg = dot_h2(mk1.z, q1.z, lg); lg = dot_h2(mk1.w, q1.w, lg);
        const uint4* drp = (const uint4*)&distsH[k * LDDH];
        const uint4* qdp = (const uint4*)&qeH[h * 64];
#pragma unroll
        for (int i = 0; i < 4; ++i) {
            uint4 a = drp[i], b = qdp[i];
            lg = dot_h2(a.x, b.x, lg); lg = dot_h2(a.y, b.y, lg);
            lg = dot_h2(a.z, b.z, lg); lg = dot_h2(a.w, b.w, lg);
        }
        const uint4* srp = (const uint4*)&seqsH[k * LDSH];
        const uint4* qsp = (const uint4*)&qeH[h * 64 + 32];
#pragma unroll
        for (int i = 0; i < 2; ++i) {
            uint4 a = srp[i], b = qsp[i];
            lg = dot_h2(a.x, b.x, lg); lg = dot_h2(a.y, b.y, lg);
            lg = dot_h2(a.z, b.z, lg); lg = dot_h2(a.w, b.w, lg);
        }
        lg *= 0.25f;   // 1/sqrt(ADIM=16)
        // logits bounded (|lg| << 88): f32 exp safe without max subtraction
        float e = __expf(lg);
        float sum = e;
#pragma unroll
        for (int off = 16; off; off >>= 1) sum += __shfl_xor(sum, off);
        attn_s[h * 36 + k] = e / sum;
    }
    __syncthreads();

    // single-pass epilogue. o-region: V read straight from L2 — idx[n*32+row] is
    // block-uniform (s_load), per-row reads coalesced across the 64 o-threads.
    ushort* od = &ovec[(size_t)n * 512];
    if (t < 64) {               // o: cols 2t,2t+1
        const int hh = t >> 3;
        const float* ap = &attn_s[hh * 36];
        const ushort* kvc = kv + 128 + 2 * t;
        const int* ib = idx + n * 32;
        float a0 = 0.f, a1 = 0.f;
#pragma unroll
        for (int i8 = 0; i8 < 8; ++i8) {
            float4 av = *(const float4*)&ap[i8 * 4];
            fma2(av.x, *(const uint*)&kvc[(size_t)ib[i8 * 4 + 0] * 256], a0, a1);
            fma2(av.y, *(const uint*)&kvc[(size_t)ib[i8 * 4 + 1] * 256], a0, a1);
            fma2(av.z, *(const uint*)&kvc[(size_t)ib[i8 * 4 + 2] * 256], a0, a1);
            fma2(av.w, *(const uint*)&kvc[(size_t)ib[i8 * 4 + 3] * 256], a0, a1);
        }
        *(uint*)&od[2 * t] = pack2h(a0, a1);
    } else if (t < 192) {       // wd: head hh, dist dims d0,d0+1
        const int i = t - 64;
        const int hh = i >> 4, d0 = (i & 15) * 2;
        const float* ap = &attn_s[hh * 36];
        const ushort* src = &distsH[d0];
        float a0 = 0.f, a1 = 0.f;
#pragma unroll
        for (int i8 = 0; i8 < 8; ++i8) {
            float4 av = *(const float4*)&ap[i8 * 4];
            fma2(av.x, *(const uint*)&src[(i8 * 4 + 0) * LDDH], a0, a1);
            fma2(av.y, *(const uint*)&src[(i8 * 4 + 1) * LDDH], a0, a1);
            fma2(av.z, *(const uint*)&src[(i8 * 4 + 2) * LDDH], a0, a1);
            fma2(av.w, *(const uint*)&src[(i8 * 4 + 3) * LDDH], a0, a1);
        }
        *(uint*)&od[128 + hh * 32 + d0] = pack2h(a0, a1);
    } else {                    // ws: head hh, seq dims s0,s0+1
        const int i = t - 192;
        const int hh = i >> 3, s0 = (i & 7) * 2;
        const float* ap = &attn_s[hh * 36];
        const ushort* src = &seqsH[s0];
        float a0 = 0.f, a1 = 0.f;
#pragma unroll
        for (int i8 = 0; i8 < 8; ++i8) {
            float4 av = *(const float4*)&ap[i8 * 4];
            fma2(av.x, *(const uint*)&src[(i8 * 4 + 0) * LDSH], a0, a1);
            fma2(av.y, *(const uint*)&src[(i8 * 4 + 1) * LDSH], a0, a1);
            fma2(av.z, *(const uint*)&src[(i8 * 4 + 2) * LDSH], a0, a1);
            fma2(av.w, *(const uint*)&src[(i8 * 4 + 3) * LDSH], a0, a1);
        }
        *(uint*)&od[384 + hh * 16 + s0] = pack2h(a0, a1);
    }
}

// ======= final (MFMA): out = features + ovec(f16)[K=512] @ BigWp(f16) + cvec =======
__global__ __launch_bounds__(256, 4) void final_kernel(
    const ushort* __restrict__ ovec, const ushort* __restrict__ BigWp,
    const float* __restrict__ cvec, const float* __restrict__ features,
    float* __restrict__ out)
{
    __shared__ __align__(16) ushort bufO[TM * LDO];  // 32 rows x 512 halves
    const int t = threadIdx.x;
    const int lane = t & 63, w = t >> 6;
    const int node0 = blockIdx.x * TM;

#pragma unroll
    for (int i = 0; i < 16; ++i) {
        int fid = t + 256 * i;          // uint4 index, 0..4095
        int row = fid >> 6, c8 = (fid & 63) * 8;
        *(uint4*)&bufO[row * LDO + c8] = *(const uint4*)&ovec[(size_t)(node0 + row) * 512 + c8];
    }
    __syncthreads();

    const int m  = (w & 1) * 16 + (lane & 15);
    const int kq = (lane >> 4) * 8;
    const int cg = w >> 1;
    const half8* bp = (const half8*)BigWp;

    floatx4 acc[4];
#pragma unroll
    for (int ct = 0; ct < 4; ++ct) acc[ct] = (floatx4){0.f, 0.f, 0.f, 0.f};

#pragma unroll
    for (int ks = 0; ks < 16; ++ks) {
        half8 afr = *(const half8*)&bufO[m * LDO + ks * 32 + kq];
#pragma unroll
        for (int ct = 0; ct < 4; ++ct) {
            const int CT = cg * 4 + ct;
            half8 bfr = bp[(CT * 16 + ks) * 64 + lane];
            acc[ct] = __builtin_amdgcn_mfma_f32_16x16x32_f16(afr, bfr, acc[ct], 0, 0, 0);
        }
    }

    // C/D: col=lane&15, row=quad*4+reg
    const int row0 = (w & 1) * 16 + ((lane >> 4) << 2);
#pragma unroll
    for (int ct = 0; ct < 4; ++ct) {
        const int col = (cg * 4 + ct) * 16 + (lane & 15);
        float cv = cvec[col];
#pragma unroll
        for (int r = 0; r < 4; ++r) {
            const size_t grow = (size_t)(node0 + row0 + r);
            out[grow * 128 + col] = acc[ct][r] + features[grow * 128 + col] + cv;
        }
    }
}

extern "C" void kernel_launch(void* const* d_in, const int* in_sizes, int n_in,
                              void* d_out, int out_size, void* d_ws, size_t ws_size,
                              hipStream_t stream)
{
    const float* features = (const float*)d_in[0];
    const float* dist     = (const float*)d_in[1];
    const float* seq      = (const float*)d_in[2];
    const float* enc      = (const float*)d_in[3];
    const int*   idx      = (const int*)d_in[4];
    const float* W1 = (const float*)d_in[5];
    const float* b1 = (const float*)d_in[6];
    const float* W2 = (const float*)d_in[7];
    const float* b2 = (const float*)d_in[8];
    const float* W3 = (const float*)d_in[9];
    const float* b3 = (const float*)d_in[10];
    const float* Wq = (const float*)d_in[11];
    const float* bq = (const float*)d_in[12];
    const float* Wk = (const float*)d_in[13];
    // d_in[14] = bk: dropped (softmax-invariant)
    const float* Wv = (const float*)d_in[15];
    const float* bv = (const float*)d_in[16];
    const float* Wo = (const float*)d_in[17];
    const float* bo = (const float*)d_in[18];
    float* out = (float*)d_out;

    // Workspace: kv 8M | qext 16M | ovec 16M | BigWp 128K | cvec 512B | wpack 192K
    char* ws = (char*)d_ws;
    ushort* kv    = (ushort*)ws;
    ushort* qext  = (ushort*)(ws + ((size_t)8  << 20));
    ushort* ovec  = (ushort*)(ws + ((size_t)24 << 20));
    ushort* BigWp = (ushort*)(ws + ((size_t)40 << 20));
    float*  cvec  = (float*)(ws + ((size_t)40 << 20) + 131072);
    ushort* wpack = (ushort*)(ws + ((size_t)40 << 20) + 131072 + 512);

    prep_kernel<<<704, 128, 0, stream>>>(Wv, Wo, bv, bo, W1, W2, W3, Wq, Wk,
                                         BigWp, cvec, wpack);
    phaseA_kernel<<<NN / TM, 256, 0, stream>>>(
        features, enc, b1, b2, b3, bq, Wk, wpack, qext, kv);
    attn_kernel<<<NN, 256, 0, stream>>>(qext, kv, dist, seq, idx, ovec);
    final_kernel<<<NN / TM, 256, 0, stream>>>(ovec, BigWp, cvec, features, out);
}